// Round 13
// baseline (339.835 us; speedup 1.0000x reference)
//
#include <hip/hip_runtime.h>
#include <hip/hip_bf16.h>

#define NB 32       // num_graphs
#define GPN 448     // split-K parts for gram (N side)
#define GPM 80      // split-K parts for gram (M side)
#define RGRP 16     // partials reduced per block in gram reduce

__device__ __forceinline__ float wave_sum(float v) {
#pragma unroll
  for (int off = 32; off; off >>= 1) v += __shfl_xor(v, off);
  return v;
}
__device__ __forceinline__ float half_sum(float v) {  // reduce within 32-lane group
#pragma unroll
  for (int off = 16; off; off >>= 1) v += __shfl_xor(v, off);
  return v;
}
__device__ __forceinline__ int wave_sum_i(int v) {
#pragma unroll
  for (int off = 32; off; off >>= 1) v += __shfl_xor(v, off);
  return v;
}

__device__ __forceinline__ float bf2f(unsigned short u) {
  return __uint_as_float(((unsigned int)u) << 16);
}
__device__ __forceinline__ unsigned short f2bf(float f) {  // RNE
  unsigned int v = __float_as_uint(f);
  return (unsigned short)((v + 0x7FFFu + ((v >> 16) & 1u)) >> 16);
}

// ---- count/rank pass: STANDALONE, int atomics only ----
__global__ void count_kernel(const int* __restrict__ ni, const int* __restrict__ ei,
                             int nnz, const int* __restrict__ xx, int eg,
                             const int* __restrict__ ee, int eeN, int* cnt_n,
                             int* cnt_e, int* cnt_gx, int* cnt_ge, int* rank_pn,
                             int* rank_pe, int* rank_g, int* rank_h) {
  int i = blockIdx.x * 1024 + (int)threadIdx.x;
#pragma unroll
  for (int k = 0; k < 4; k++, i += 256) {
    if (i < nnz) {
      const int n = ni[i], e = ei[i];
      rank_pn[i] = atomicAdd(&cnt_n[n], 1);
      rank_pe[i] = atomicAdd(&cnt_e[e], 1);
    } else if (i < nnz + eg) {
      const int j = i - nnz;
      rank_g[j] = atomicAdd(&cnt_gx[xx[eg + j]], 1);
    } else if (i < nnz + eg + eeN) {
      const int j = i - nnz - eg;
      rank_h[j] = atomicAdd(&cnt_ge[ee[eeN + j]], 1);
    }
  }
}

// ---- dual GEMM body: out1 = bf16(X@W1 + b1), out2 = bf16(X@W2) ----
// 64-row bf16 LDS tile, row padded to 136 shorts (272B, 16B-aligned).
// Inner loop reads 4 k-values per ds_read_b64 (broadcast within half-wave).
__device__ __forceinline__ void gemm_body(const float* __restrict__ X,
                                          const float* __restrict__ W1,
                                          const float* __restrict__ b1,
                                          unsigned short* __restrict__ out1,
                                          const float* __restrict__ W2,
                                          unsigned short* __restrict__ out2, int rows,
                                          int blk, unsigned short (*xs)[136]) {
  const int t = threadIdx.x;
  const int c4 = t & 31;
  const int rg = t >> 5;
  const int r0 = blk * 64;
#pragma unroll
  for (int i = 0; i < 8; i++) {
    const int idx = t + i * 256;
    const int row = idx >> 5, cc = idx & 31;
    const int gr = r0 + row;
    float4 v = make_float4(0.f, 0.f, 0.f, 0.f);
    if (gr < rows) v = ((const float4*)X)[(size_t)gr * 32 + cc];
    ushort4 u;
    u.x = f2bf(v.x); u.y = f2bf(v.y); u.z = f2bf(v.z); u.w = f2bf(v.w);
    *(ushort4*)&xs[row][cc * 4] = u;
  }
  __syncthreads();
  const float4* W1v = (const float4*)W1;
  const float4* W2v = (const float4*)W2;
  const float4 b4 = ((const float4*)b1)[c4];
  float4 acc1[8], acc2[8];
#pragma unroll
  for (int i = 0; i < 8; i++) {
    acc1[i] = b4;
    acc2[i] = make_float4(0.f, 0.f, 0.f, 0.f);
  }
  const int rbase = rg * 8;
  for (int kb = 0; kb < 32; kb++) {  // 4 k-values per iteration
    float4 w1v[4], w2v[4];
#pragma unroll
    for (int q = 0; q < 4; q++) {
      w1v[q] = W1v[(kb * 4 + q) * 32 + c4];
      w2v[q] = W2v[(kb * 4 + q) * 32 + c4];
    }
#pragma unroll
    for (int i = 0; i < 8; i++) {
      const uint2 rd = *(const uint2*)&xs[rbase + i][kb * 4];
      const float x0 = __uint_as_float(rd.x << 16);
      const float x1 = __uint_as_float(rd.x & 0xffff0000u);
      const float x2 = __uint_as_float(rd.y << 16);
      const float x3 = __uint_as_float(rd.y & 0xffff0000u);
      acc1[i].x = fmaf(x0, w1v[0].x, acc1[i].x);
      acc1[i].y = fmaf(x0, w1v[0].y, acc1[i].y);
      acc1[i].z = fmaf(x0, w1v[0].z, acc1[i].z);
      acc1[i].w = fmaf(x0, w1v[0].w, acc1[i].w);
      acc2[i].x = fmaf(x0, w2v[0].x, acc2[i].x);
      acc2[i].y = fmaf(x0, w2v[0].y, acc2[i].y);
      acc2[i].z = fmaf(x0, w2v[0].z, acc2[i].z);
      acc2[i].w = fmaf(x0, w2v[0].w, acc2[i].w);
      acc1[i].x = fmaf(x1, w1v[1].x, acc1[i].x);
      acc1[i].y = fmaf(x1, w1v[1].y, acc1[i].y);
      acc1[i].z = fmaf(x1, w1v[1].z, acc1[i].z);
      acc1[i].w = fmaf(x1, w1v[1].w, acc1[i].w);
      acc2[i].x = fmaf(x1, w2v[1].x, acc2[i].x);
      acc2[i].y = fmaf(x1, w2v[1].y, acc2[i].y);
      acc2[i].z = fmaf(x1, w2v[1].z, acc2[i].z);
      acc2[i].w = fmaf(x1, w2v[1].w, acc2[i].w);
      acc1[i].x = fmaf(x2, w1v[2].x, acc1[i].x);
      acc1[i].y = fmaf(x2, w1v[2].y, acc1[i].y);
      acc1[i].z = fmaf(x2, w1v[2].z, acc1[i].z);
      acc1[i].w = fmaf(x2, w1v[2].w, acc1[i].w);
      acc2[i].x = fmaf(x2, w2v[2].x, acc2[i].x);
      acc2[i].y = fmaf(x2, w2v[2].y, acc2[i].y);
      acc2[i].z = fmaf(x2, w2v[2].z, acc2[i].z);
      acc2[i].w = fmaf(x2, w2v[2].w, acc2[i].w);
      acc1[i].x = fmaf(x3, w1v[3].x, acc1[i].x);
      acc1[i].y = fmaf(x3, w1v[3].y, acc1[i].y);
      acc1[i].z = fmaf(x3, w1v[3].z, acc1[i].z);
      acc1[i].w = fmaf(x3, w1v[3].w, acc1[i].w);
      acc2[i].x = fmaf(x3, w2v[3].x, acc2[i].x);
      acc2[i].y = fmaf(x3, w2v[3].y, acc2[i].y);
      acc2[i].z = fmaf(x3, w2v[3].z, acc2[i].z);
      acc2[i].w = fmaf(x3, w2v[3].w, acc2[i].w);
    }
  }
#pragma unroll
  for (int i = 0; i < 8; i++) {
    const int gr = r0 + rbase + i;
    if (gr < rows) {
      ushort4 o1, o2;
      o1.x = f2bf(acc1[i].x); o1.y = f2bf(acc1[i].y);
      o1.z = f2bf(acc1[i].z); o1.w = f2bf(acc1[i].w);
      o2.x = f2bf(acc2[i].x); o2.y = f2bf(acc2[i].y);
      o2.z = f2bf(acc2[i].z); o2.w = f2bf(acc2[i].w);
      ((ushort4*)out1)[(size_t)gr * 32 + c4] = o1;
      ((ushort4*)out2)[(size_t)gr * 32 + c4] = o2;
    }
  }
}

// ---- multi-block segmented exclusive scan over the 4 count arrays ----
__global__ __launch_bounds__(256) void scan_partial(
    const int* __restrict__ c0, int n0, const int* __restrict__ c1, int n1,
    const int* __restrict__ c2, int n2, const int* __restrict__ c3, int n3,
    int nb0, int nb1, int nb2, int nb3, int* __restrict__ bsums) {
  const int gb = blockIdx.x;
  const int* cnt;
  int lb, n;
  if (gb < nb0) { cnt = c0; lb = gb; n = n0; }
  else if (gb < nb0 + nb1) { cnt = c1; lb = gb - nb0; n = n1; }
  else if (gb < nb0 + nb1 + nb2) { cnt = c2; lb = gb - nb0 - nb1; n = n2; }
  else { cnt = c3; lb = gb - nb0 - nb1 - nb2; n = n3; }
  const int t = threadIdx.x;
  const int base = lb * 4096 + t * 16;
  int s = 0;
#pragma unroll
  for (int i = 0; i < 16; i++) {
    const int idx = base + i;
    if (idx < n) s += cnt[idx];
  }
  const int wsum = wave_sum_i(s);
  __shared__ int wsm[4];
  if ((t & 63) == 0) wsm[t >> 6] = wsum;
  __syncthreads();
  if (t == 0) bsums[gb] = wsm[0] + wsm[1] + wsm[2] + wsm[3];
}

__global__ void scan_bsums(const int* __restrict__ bsums, int nb0, int nb1, int nb2,
                           int nb3, int* __restrict__ bbase, int* __restrict__ totals) {
  if (threadIdx.x) return;
  int segs[4] = {nb0, nb1, nb2, nb3};
  int gb = 0;
  for (int a = 0; a < 4; a++) {
    int run = 0;
    for (int i = 0; i < segs[a]; i++) {
      bbase[gb] = run;
      run += bsums[gb];
      gb++;
    }
    totals[a] = run;
  }
}

// rowptr + optional rsqrt(1+deg)
__global__ __launch_bounds__(256) void scan_final(
    int* __restrict__ c0, int* rp0, float* rs0, int n0,
    int* __restrict__ c1, int* rp1, float* rs1, int n1,
    int* __restrict__ c2, int* rp2, float* rs2, int n2,
    int* __restrict__ c3, int* rp3, float* rs3, int n3,
    int nb0, int nb1, int nb2, int nb3, const int* __restrict__ bbase,
    const int* __restrict__ totals) {
  const int gb = blockIdx.x;
  int* cnt;
  int* rp;
  float* rs;
  int lb, n, a;
  if (gb < nb0) { cnt = c0; rp = rp0; rs = rs0; lb = gb; n = n0; a = 0; }
  else if (gb < nb0 + nb1) { cnt = c1; rp = rp1; rs = rs1; lb = gb - nb0; n = n1; a = 1; }
  else if (gb < nb0 + nb1 + nb2) { cnt = c2; rp = rp2; rs = rs2; lb = gb - nb0 - nb1; n = n2; a = 2; }
  else { cnt = c3; rp = rp3; rs = rs3; lb = gb - nb0 - nb1 - nb2; n = n3; a = 3; }
  const int t = threadIdx.x;
  const int base = lb * 4096 + t * 16;
  int vals[16];
  int s = 0;
#pragma unroll
  for (int i = 0; i < 16; i++) {
    const int idx = base + i;
    vals[i] = (idx < n) ? cnt[idx] : 0;
    s += vals[i];
  }
  __shared__ int tsum[256];
  tsum[t] = s;
  __syncthreads();
  for (int off = 1; off < 256; off <<= 1) {
    const int v = (t >= off) ? tsum[t - off] : 0;
    __syncthreads();
    tsum[t] += v;
    __syncthreads();
  }
  int run = bbase[gb] + (t ? tsum[t - 1] : 0);
#pragma unroll
  for (int i = 0; i < 16; i++) {
    const int idx = base + i;
    if (idx < n) {
      rp[idx] = run;
      if (rs) rs[idx] = rsqrtf(1.f + (float)vals[i]);
      run += vals[i];
    }
  }
  if (t == 0 && lb == 0) rp[n] = totals[a];
}

// ---- GEMMs || fill (atomic-free) || batch_counts, one launch ----
__global__ __launch_bounds__(256) void fused_fill_gemm(
    const float* __restrict__ x, const float* __restrict__ Wv,
    const float* __restrict__ bv, unsigned short* __restrict__ xw,
    const float* __restrict__ Wx, unsigned short* __restrict__ xw2, int N, int nbGN,
    const float* __restrict__ hf, const float* __restrict__ We,
    const float* __restrict__ be, unsigned short* __restrict__ ew,
    const float* __restrict__ Weg, unsigned short* __restrict__ ew2, int M, int nbG,
    const int* __restrict__ ni, const int* __restrict__ ei, int nnz,
    const int* __restrict__ xx, int eg, const int* __restrict__ ee, int eeN,
    const int* __restrict__ rp_n, const int* __restrict__ rp_e,
    const int* __restrict__ rp_gx, const int* __restrict__ rp_ge,
    const int* __restrict__ rank_pn, const int* __restrict__ rank_pe,
    const int* __restrict__ rank_g, const int* __restrict__ rank_h, int* adj_n,
    int* adj_e, int* adj_gx, int* adj_ge, int nbFill, const int* __restrict__ nbi,
    int* cbn, const int* __restrict__ hbi, int* cbe) {
  __shared__ unsigned short xs[64][136];
  const int b = blockIdx.x;
  const int t = threadIdx.x;
  if (b < nbG) {
    if (b < nbGN)
      gemm_body(x, Wv, bv, xw, Wx, xw2, N, b, xs);
    else
      gemm_body(hf, We, be, ew, Weg, ew2, M, b - nbGN, xs);
    return;
  }
  const int fb = b - nbG;
  if (fb < nbFill) {
    int i = fb * 1024 + t;
#pragma unroll
    for (int k = 0; k < 4; k++, i += 256) {
      if (i < nnz) {
        const int n0 = ni[i], e0 = ei[i];
        adj_n[rp_n[n0] + rank_pn[i]] = e0;
        adj_e[rp_e[e0] + rank_pe[i]] = n0;
      } else if (i < nnz + eg) {
        const int j = i - nnz;
        adj_gx[rp_gx[xx[eg + j]] + rank_g[j]] = xx[j];
      } else if (i < nnz + eg + eeN) {
        const int j = i - nnz - eg;
        adj_ge[rp_ge[ee[eeN + j]] + rank_h[j]] = ee[j];
      }
    }
    return;
  }
  const bool B = (fb - nbFill) != 0;
  const int* idx = B ? hbi : nbi;
  const int nn = B ? M : N;
  int* out = B ? cbe : cbn;
  const int g = t;
  if (g >= NB) return;
  int lo = 0, hi = nn;
  while (lo < hi) { int mid = (lo + hi) >> 1; if (idx[mid] < g) lo = mid + 1; else hi = mid; }
  const int l = lo;
  lo = 0; hi = nn;
  while (lo < hi) { int mid = (lo + hi) >> 1; if (idx[mid] < g + 1) lo = mid + 1; else hi = mid; }
  out[g] = lo - l;
}

// ---- ecoord: CSR mean of member coords ----
__global__ __launch_bounds__(256) void ecoord_gather(
    const float* __restrict__ coord, const int* __restrict__ rp_e,
    const int* __restrict__ adj_e, float* __restrict__ ecoord, int m) {
  const int e = (blockIdx.x * 256 + (int)threadIdx.x) >> 6;
  const int lane = threadIdx.x & 63;
  if (e >= m) return;
  const int lo = rp_e[e], hi = rp_e[e + 1];
  float cacc = 0.f;
  for (int base = lo; base < hi; base += 64) {
    const int mm = min(64, hi - base);
    int aj = (base + lane < hi) ? adj_e[base + lane] : 0;
    for (int j = 0; j < mm; j++) {
      const int nidx = __shfl(aj, j);
      if (lane < 3) cacc += coord[nidx * 3 + lane];
    }
  }
  if (lane < 3) ecoord[e * 3 + lane] = cacc / fmaxf((float)(hi - lo), 1.f);
}

// ---- GCN gather body: HALF-WAVE per row (32 lanes x ushort4 = 256B) ----
__device__ __forceinline__ void gcn_body(const unsigned short* __restrict__ xw,
                                         const int* __restrict__ rowptr,
                                         const int* __restrict__ adj,
                                         const float* __restrict__ rs,
                                         const float* __restrict__ bias,
                                         float* __restrict__ out, int n, int lb) {
  const int r = (lb * 256 + (int)threadIdx.x) >> 5;
  const int lane = threadIdx.x & 31;
  if (r >= n) return;
  const int lo = rowptr[r], hi = rowptr[r + 1];
  const float rd = rs[r];
  float4 acc = make_float4(0.f, 0.f, 0.f, 0.f);
  for (int base = lo; base < hi; base += 32) {
    const int mm = min(32, hi - base);
    int aj = 0;
    float rj = 0.f;
    if (base + lane < hi) {
      aj = adj[base + lane];
      rj = rs[aj];
    }
    for (int j = 0; j < mm; j++) {
      const int s = __shfl(aj, j, 32);
      const float w = __shfl(rj, j, 32);
      const ushort4 u = ((const ushort4*)xw)[(size_t)s * 32 + lane];
      acc.x = fmaf(w, bf2f(u.x), acc.x);
      acc.y = fmaf(w, bf2f(u.y), acc.y);
      acc.z = fmaf(w, bf2f(u.z), acc.z);
      acc.w = fmaf(w, bf2f(u.w), acc.w);
    }
  }
  const ushort4 su = ((const ushort4*)xw)[(size_t)r * 32 + lane];
  const float4 bb = ((const float4*)bias)[lane];
  float4 o;
  o.x = fmaf(rd, acc.x, fmaf(rd * rd, bf2f(su.x), bb.x));
  o.y = fmaf(rd, acc.y, fmaf(rd * rd, bf2f(su.y), bb.y));
  o.z = fmaf(rd, acc.z, fmaf(rd * rd, bf2f(su.z), bb.z));
  o.w = fmaf(rd, acc.w, fmaf(rd * rd, bf2f(su.w), bb.w));
  ((float4*)out)[(size_t)r * 32 + lane] = o;
}

// ---- all four gathers in one launch (half-wave per row) ----
__global__ __launch_bounds__(256) void fused_gathers(
    const unsigned short* __restrict__ ew, const unsigned short* __restrict__ xw,
    const float* __restrict__ coord, const float* __restrict__ ecoord,
    const int* __restrict__ rp_n, const int* __restrict__ adj_n,
    float* __restrict__ z_conv, float* __restrict__ outc, int N, int nbNode,
    const unsigned short* __restrict__ xw2, const int* __restrict__ rp_gx,
    const int* __restrict__ adj_gx, const float* __restrict__ rs_gx,
    const float* __restrict__ bx, float* __restrict__ outz, int nbGcnN,
    const unsigned short* __restrict__ ew2, const int* __restrict__ rp_ge,
    const int* __restrict__ adj_ge, const float* __restrict__ rs_ge,
    const float* __restrict__ beg, float* __restrict__ oute, int M, int nbGcnM,
    const int* __restrict__ rp_e, const int* __restrict__ adj_e,
    float* __restrict__ e_conv) {
  const int b = blockIdx.x;
  const int t = threadIdx.x;
  const int lane = t & 31;
  if (b < nbNode) {
    const int r = (b * 256 + t) >> 5;
    if (r >= N) return;
    const int lo = rp_n[r], hi = rp_n[r + 1];
    const ushort4 au = ((const ushort4*)xw)[(size_t)r * 32 + lane];
    const float a0 = bf2f(au.x), a1 = bf2f(au.y), a2 = bf2f(au.z), a3 = bf2f(au.w);
    const float myc = (lane < 3) ? coord[r * 3 + lane] : 0.f;
    float4 acc = make_float4(0.f, 0.f, 0.f, 0.f);
    float cacc = 0.f;
    for (int base = lo; base < hi; base += 32) {
      const int mm = min(32, hi - base);
      int aj = (base + lane < hi) ? adj_n[base + lane] : 0;
      for (int j = 0; j < mm; j++) {
        const int e = __shfl(aj, j, 32);
        const ushort4 bu = ((const ushort4*)ew)[(size_t)e * 32 + lane];
        const float b0 = bf2f(bu.x), b1 = bf2f(bu.y), b2 = bf2f(bu.z), b3 = bf2f(bu.w);
        acc.x += b0;
        acc.y += b1;
        acc.z += b2;
        acc.w += b3;
        float dot = fmaf(a0, b0, fmaf(a1, b1, fmaf(a2, b2, a3 * b3)));
        dot = half_sum(dot);
        const float ph = tanhf(dot * 0.08838834764831845f);  // 1/sqrt(128)
        if (lane < 3) cacc = fmaf(myc - ecoord[e * 3 + lane], ph, cacc);
      }
    }
    const float inv = 1.f / fmaxf((float)(hi - lo), 1.f);
    float4 o;
    o.x = acc.x * inv;
    o.y = acc.y * inv;
    o.z = acc.z * inv;
    o.w = acc.w * inv;
    ((float4*)z_conv)[(size_t)r * 32 + lane] = o;
    if (lane < 3) outc[r * 3 + lane] = myc + cacc * inv;
    return;
  }
  if (b < nbNode + nbGcnN) {
    gcn_body(xw2, rp_gx, adj_gx, rs_gx, bx, outz, N, b - nbNode);
    return;
  }
  if (b < nbNode + nbGcnN + nbGcnM) {
    gcn_body(ew2, rp_ge, adj_ge, rs_ge, beg, oute, M, b - nbNode - nbGcnN);
    return;
  }
  // hedge path
  const int lb = b - nbNode - nbGcnN - nbGcnM;
  const int e = (lb * 256 + t) >> 5;
  if (e >= M) return;
  const int lo = rp_e[e], hi = rp_e[e + 1];
  float4 acc = make_float4(0.f, 0.f, 0.f, 0.f);
  for (int base = lo; base < hi; base += 32) {
    const int mm = min(32, hi - base);
    int aj = (base + lane < hi) ? adj_e[base + lane] : 0;
    for (int j = 0; j < mm; j++) {
      const int nidx = __shfl(aj, j, 32);
      const ushort4 vu = ((const ushort4*)xw)[(size_t)nidx * 32 + lane];
      acc.x += bf2f(vu.x);
      acc.y += bf2f(vu.y);
      acc.z += bf2f(vu.z);
      acc.w += bf2f(vu.w);
    }
  }
  const float inv = 1.f / fmaxf((float)(hi - lo), 1.f);
  float4 o;
  o.x = acc.x * inv;
  o.y = acc.y * inv;
  o.z = acc.z * inv;
  o.w = acc.w * inv;
  ((float4*)e_conv)[(size_t)e * 32 + lane] = o;
}

// ---------- barlow: split-K gram + fused colstats ----------
__global__ __launch_bounds__(256) void gram_partial2(
    const float* __restrict__ Z1a, const float* __restrict__ Z2a, int na,
    float* __restrict__ parta, const float* __restrict__ Z1b,
    const float* __restrict__ Z2b, int nbm, float* __restrict__ partb,
    float* __restrict__ st, int nblkA) {
  const bool A = (int)blockIdx.x < nblkA;
  const int pid = A ? blockIdx.x : blockIdx.x - nblkA;
  const float* Z1 = A ? Z1a : Z1b;
  const float* Z2 = A ? Z2a : Z2b;
  const int n = A ? na : nbm;
  const int gparts = A ? GPN : GPM;
  float* part = (A ? parta : partb) + (size_t)pid * 16384;
  float* sum1 = st + (A ? 0 : 512);
  float* ssq1 = sum1 + 128;
  float* sum2 = sum1 + 256;
  float* ssq2 = sum1 + 384;
  __shared__ float4 s1[256], s2[256];
  const int t = threadIdx.x;
  const int ti = t >> 4, tj = t & 15;
  const int rpb = (n + gparts - 1) / gparts;
  const int lo = pid * rpb, hi = min(lo + rpb, n);
  float acc[8][8];
#pragma unroll
  for (int i = 0; i < 8; i++)
#pragma unroll
    for (int j = 0; j < 8; j++) acc[i][j] = 0.f;
  float cs = 0.f, cq = 0.f;
  const float* s1f = (const float*)s1;
  const float* s2f = (const float*)s2;
  const int c = t & 127;
  const bool low = t < 128;
  for (int rb = lo; rb < hi; rb += 8) {
    const int nr = min(8, hi - rb);
    __syncthreads();
    if (t < nr * 32) {
      const int rr = rb + (t >> 5);
      s1[t] = ((const float4*)Z1)[(size_t)rr * 32 + (t & 31)];
      s2[t] = ((const float4*)Z2)[(size_t)rr * 32 + (t & 31)];
    }
    __syncthreads();
    for (int r = 0; r < nr; r++) {
      const float4 a0 = s1[r * 32 + ti * 2], a1 = s1[r * 32 + ti * 2 + 1];
      const float4 b0 = s2[r * 32 + tj * 2], b1 = s2[r * 32 + tj * 2 + 1];
      const float av[8] = {a0.x, a0.y, a0.z, a0.w, a1.x, a1.y, a1.z, a1.w};
      const float bv[8] = {b0.x, b0.y, b0.z, b0.w, b1.x, b1.y, b1.z, b1.w};
#pragma unroll
      for (int i = 0; i < 8; i++)
#pragma unroll
        for (int j = 0; j < 8; j++) acc[i][j] = fmaf(av[i], bv[j], acc[i][j]);
      const float v = low ? s1f[r * 128 + c] : s2f[r * 128 + c];
      cs += v;
      cq = fmaf(v, v, cq);
    }
  }
  float4* P = (float4*)part;
#pragma unroll
  for (int i = 0; i < 8; i++) {
    P[(ti * 8 + i) * 32 + tj * 2] = make_float4(acc[i][0], acc[i][1], acc[i][2], acc[i][3]);
    P[(ti * 8 + i) * 32 + tj * 2 + 1] = make_float4(acc[i][4], acc[i][5], acc[i][6], acc[i][7]);
  }
  if (low) {
    atomicAdd(&sum1[c], cs);
    atomicAdd(&ssq1[c], cq);
  } else {
    atomicAdd(&sum2[c], cs);
    atomicAdd(&ssq2[c], cq);
  }
}

// ---- gram hierarchical reduce + layernorm/gelu/residual, one launch ----
__global__ __launch_bounds__(256) void fused_reduce_ln(
    const float* __restrict__ parta, float* __restrict__ G1,
    const float* __restrict__ partb, float* __restrict__ G2,
    const float* __restrict__ convA, const float* __restrict__ residA,
    float* __restrict__ outA, int nA, int lnA, const float* __restrict__ convB,
    const float* __restrict__ residB, float* __restrict__ outB, int nBm,
    const float* __restrict__ g, const float* __restrict__ bvec) {
  const int b = blockIdx.x;
  const int t = threadIdx.x;
  const int NRED = (GPN / RGRP + GPM / RGRP) * 16;  // 528
  if (b < NRED) {
    const int nga = GPN / RGRP;
    const int slice = b & 15;
    const int grp = b >> 4;
    const bool A = grp < nga;
    const float* part = A ? parta : partb;
    float* G = A ? G1 : G2;
    const int g0 = (A ? grp : grp - nga) * RGRP;
    const int e = slice * 1024 + t * 4;
    float4 s = make_float4(0.f, 0.f, 0.f, 0.f);
#pragma unroll 4
    for (int p = 0; p < RGRP; p++) {
      const float4 v = *(const float4*)&part[(size_t)(g0 + p) * 16384 + e];
      s.x += v.x;
      s.y += v.y;
      s.z += v.z;
      s.w += v.w;
    }
    atomicAdd(&G[e], s.x);
    atomicAdd(&G[e + 1], s.y);
    atomicAdd(&G[e + 2], s.z);
    atomicAdd(&G[e + 3], s.w);
    return;
  }
  const int b2 = b - NRED;
  const bool A = b2 < lnA;
  const int lb = A ? b2 : b2 - lnA;
  const float* conv = A ? convA : convB;
  const float* resid = A ? residA : residB;
  float* out = A ? outA : outB;
  const int rows = A ? nA : nBm;
  const int w = (lb * 256 + t) >> 6;
  const int lane = t & 63;
  if (w >= rows) return;
  const float2 v = ((const float2*)conv)[(size_t)w * 64 + lane];
  const float m = wave_sum(v.x + v.y) * (1.f / 128.f);
  const float q = wave_sum(fmaf(v.x, v.x, v.y * v.y)) * (1.f / 128.f);
  const float rstd = rsqrtf(q - m * m + 1e-5f);
  const float2 gg = ((const float2*)g)[lane];
  const float2 bb = ((const float2*)bvec)[lane];
  const float2 rr = ((const float2*)resid)[(size_t)w * 64 + lane];
  float y0 = fmaf(gg.x, (v.x - m) * rstd, bb.x);
  float y1 = fmaf(gg.y, (v.y - m) * rstd, bb.y);
  y0 = 0.5f * y0 * (1.f + erff(y0 * 0.7071067811865476f));
  y1 = 0.5f * y1 * (1.f + erff(y1 * 0.7071067811865476f));
  float2 o;
  o.x = y0 + rr.x;
  o.y = y1 + rr.y;
  ((float2*)out)[(size_t)w * 64 + lane] = o;
}

// ---- barlow finalize + segment pooling, one launch ----
__global__ __launch_bounds__(256) void fused_fin_pool(
    const float* __restrict__ G1, const float* __restrict__ G2,
    const float* __restrict__ st, float nA, float nB, float* outbt,
    const float* __restrict__ ZA, const int* __restrict__ bidxA, int n, int spA,
    float* poolA, const float* __restrict__ ZB, const int* __restrict__ bidxB, int m,
    float* poolB) {
  __shared__ float s1s[128], m1s[128], s2s[128], m2s[128];
  __shared__ float red[256];
  const int b = blockIdx.x;
  const int t = threadIdx.x;
  if (b < 2) {
    const bool A = b == 0;
    const float* G = A ? G1 : G2;
    const float* sum1 = st + (A ? 0 : 512);
    const float* ssq1 = sum1 + 128;
    const float* sum2 = sum1 + 256;
    const float* ssq2 = sum1 + 384;
    const float nn = A ? nA : nB;
    if (t < 128) {
      const float inv_n = 1.f / nn;
      const float bnf = (nn - 1.f) * inv_n + 1e-5f;
      float mu = sum1[t] * inv_n;
      float vu = (ssq1[t] * inv_n - mu * mu) * nn / (nn - 1.f);
      s1s[t] = rsqrtf(vu * bnf);
      m1s[t] = mu;
      mu = sum2[t] * inv_n;
      vu = (ssq2[t] * inv_n - mu * mu) * nn / (nn - 1.f);
      s2s[t] = rsqrtf(vu * bnf);
      m2s[t] = mu;
    }
    __syncthreads();
    float on = 0.f, off = 0.f;
    for (int idx = t; idx < 16384; idx += 256) {
      const int i = idx >> 7, j = idx & 127;
      const float c = s1s[i] * s2s[j] * (G[idx] - nn * m1s[i] * m2s[j]) * (1.f / 32.f);
      if (i == j) {
        const float dd = c - 1.f;
        on += dd * dd;
      } else {
        off += c * c;
      }
    }
    red[t] = on + 0.005f * off;
    __syncthreads();
    for (int s = 128; s; s >>= 1) {
      if (t < s) red[t] += red[t + s];
      __syncthreads();
    }
    if (t == 0) atomicAdd(outbt, red[0]);
    return;
  }
  const int pb = b - 2;
  const bool A = pb < spA;
  const int lb = A ? pb : pb - spA;
  const float* Z = A ? ZA : ZB;
  const int* bidx = A ? bidxA : bidxB;
  const int n2 = A ? n : m;
  float* pool = A ? poolA : poolB;
  const int c = t & 127;
  const int h = t >> 7;
  const int r0 = lb * 128 + h * 64;
  const int re = min(lb * 128 + (h + 1) * 64, n2);
  if (r0 >= n2) return;
  float acc = 0.f;
  int cur = bidx[r0];
  for (int r = r0; r < re; r++) {
    const int bb = bidx[r];
    if (bb != cur) {
      atomicAdd(&pool[cur * 128 + c], acc);
      acc = 0.f;
      cur = bb;
    }
    acc += Z[(size_t)r * 128 + c];
  }
  atomicAdd(&pool[cur * 128 + c], acc);
}

__global__ __launch_bounds__(128) void graph_gemm(
    const float* __restrict__ zg, const float* __restrict__ eg,
    const int* __restrict__ cnz, const int* __restrict__ cne,
    const float* __restrict__ Wf, const float* __restrict__ bf, float* out) {
  __shared__ float cat[256];
  const int g = blockIdx.x, t = threadIdx.x;
  cat[t] = zg[g * 128 + t] / fmaxf((float)cnz[g], 1.f);
  cat[128 + t] = eg[g * 128 + t] / fmaxf((float)cne[g], 1.f);
  __syncthreads();
  float acc = bf[t];
#pragma unroll 8
  for (int k = 0; k < 256; k++) acc = fmaf(cat[k], Wf[k * 128 + t], acc);
  out[g * 128 + t] = acc;
}

extern "C" void kernel_launch(void* const* d_in, const int* in_sizes, int n_in,
                              void* d_out, int out_size, void* d_ws, size_t ws_size,
                              hipStream_t stream) {
  const float* x = (const float*)d_in[0];
  const float* hf = (const float*)d_in[1];
  const float* coord = (const float*)d_in[2];
  const int* ni = (const int*)d_in[3];
  const int* ei = (const int*)d_in[4];
  const int* nb = (const int*)d_in[5];
  const int* hb = (const int*)d_in[6];
  const int* xx = (const int*)d_in[7];
  const int* ee = (const int*)d_in[8];
  const float* Wv = (const float*)d_in[10];
  const float* bv = (const float*)d_in[11];
  const float* We = (const float*)d_in[12];
  const float* be = (const float*)d_in[13];
  const float* Wx = (const float*)d_in[14];
  const float* bx = (const float*)d_in[15];
  const float* Weg = (const float*)d_in[16];
  const float* beg = (const float*)d_in[17];
  const float* lng = (const float*)d_in[18];
  const float* lnb = (const float*)d_in[19];
  const float* Wf = (const float*)d_in[20];
  const float* bf = (const float*)d_in[21];

  const int N = in_sizes[0] / 128;
  const int M = in_sizes[1] / 128;
  const int NNZ = in_sizes[3];
  const int EG = in_sizes[7] / 2;
  const int EE = in_sizes[8] / 2;

  float* ws = (float*)d_ws;
  size_t o = 0;
  // --- pool of buffers dead by gram time (aliased as gram partials) ---
  unsigned short* xw = (unsigned short*)(ws + o);  o += (size_t)N * 64;  // bf16 N×128
  unsigned short* ew = (unsigned short*)(ws + o);  o += (size_t)M * 64;
  unsigned short* xw2 = (unsigned short*)(ws + o); o += (size_t)N * 64;
  unsigned short* ew2 = (unsigned short*)(ws + o); o += (size_t)M * 64;
  int* rank_pn = (int*)(ws + o); o += NNZ;
  int* rank_pe = (int*)(ws + o); o += NNZ;
  int* rank_g = (int*)(ws + o);  o += EG;
  int* rank_h = (int*)(ws + o);  o += EE;
  // pool >= (GPN+GPM)*16384 floats
  // --- live buffers ---
  float* z_conv = ws + o; o += (size_t)N * 128;
  float* e_conv = ws + o; o += (size_t)M * 128;
  float* rs_gx = ws + o;  o += N;
  float* rs_ge = ws + o;  o += M;
  float* ecoord = ws + o; o += (size_t)M * 3;  // written by ecoord_gather
  const size_t fz0 = o;  // zeroed float block
  float* G1 = ws + o;     o += 16384;          // accumulated by fused_reduce_ln
  float* G2 = ws + o;     o += 16384;
  float* st = ws + o;     o += 1024;
  float* zg = ws + o;     o += NB * 128;
  float* eg_p = ws + o;   o += NB * 128;
  const size_t fz1 = o;
  int* wsi = (int*)(ws + o);
  size_t oi = 0;
  int* cnt_n = wsi + oi;  oi += N;  // zeroed: counts after count_kernel
  int* cnt_e = wsi + oi;  oi += M;
  int* cnt_gx = wsi + oi; oi += N;
  int* cnt_ge = wsi + oi; oi += M;
  const size_t iz1 = oi;
  int* rp_n = wsi + oi;   oi += N + 1;
  int* rp_e = wsi + oi;   oi += M + 1;
  int* rp_gx = wsi + oi;  oi += N + 1;
  int* rp_ge = wsi + oi;  oi += M + 1;
  int* adj_n = wsi + oi;  oi += NNZ;
  int* adj_e = wsi + oi;  oi += NNZ;
  int* adj_gx = wsi + oi; oi += EG;
  int* adj_ge = wsi + oi; oi += EE;
  int* cbn = wsi + oi;    oi += NB;
  int* cbe = wsi + oi;    oi += NB;
  int* bsums = wsi + oi;  oi += 64;
  int* bbase = wsi + oi;  oi += 64;
  int* totals = wsi + oi; oi += 4;

  float* gpartA = ws;                        // GPN*16384 floats (aliases dead pool)
  float* gpartB = ws + (size_t)GPN * 16384;  // GPM*16384 floats

  float* outz = (float*)d_out;           // temporarily z_imp
  float* oute = outz + (size_t)N * 128;  // temporarily e_imp
  float* outc = oute + (size_t)M * 128;
  float* outg = outc + (size_t)N * 3;
  float* outbt = outg + NB * 128;

  hipMemsetAsync(ws + fz0, 0, (fz1 - fz0) * 4, stream);
  hipMemsetAsync(wsi, 0, iz1 * 4, stream);
  hipMemsetAsync(outbt, 0, 4, stream);

  // 1) count/rank pass (int atomics only)
  const int tot = NNZ + EG + EE;
  const int nbCnt = (tot + 1023) >> 10;
  count_kernel<<<nbCnt, 256, 0, stream>>>(ni, ei, NNZ, xx, EG, ee, EE, cnt_n, cnt_e,
                                          cnt_gx, cnt_ge, rank_pn, rank_pe, rank_g,
                                          rank_h);

  // 2) scans
  const int nb0 = (N + 4095) >> 12, nb1 = (M + 4095) >> 12;
  const int sgrid = 2 * nb0 + 2 * nb1;
  scan_partial<<<sgrid, 256, 0, stream>>>(cnt_n, N, cnt_e, M, cnt_gx, N, cnt_ge, M,
                                          nb0, nb1, nb0, nb1, bsums);
  scan_bsums<<<1, 64, 0, stream>>>(bsums, nb0, nb1, nb0, nb1, bbase, totals);
  scan_final<<<sgrid, 256, 0, stream>>>(cnt_n, rp_n, nullptr, N, cnt_e, rp_e, nullptr,
                                        M, cnt_gx, rp_gx, rs_gx, N, cnt_ge, rp_ge,
                                        rs_ge, M, nb0, nb1, nb0, nb1, bbase, totals);

  // 3) GEMMs || fill (atomic-free) || batch counts
  const int nbGN = (N + 63) / 64, nbGM = (M + 63) / 64;
  const int nbG = nbGN + nbGM;
  const int nbFill = (tot + 1023) >> 10;
  fused_fill_gemm<<<nbG + nbFill + 2, 256, 0, stream>>>(
      x, Wv, bv, xw, Wx, xw2, N, nbGN, hf, We, be, ew, Weg, ew2, M, nbG, ni, ei, NNZ,
      xx, EG, ee, EE, rp_n, rp_e, rp_gx, rp_ge, rank_pn, rank_pe, rank_g, rank_h,
      adj_n, adj_e, adj_gx, adj_ge, nbFill, nb, cbn, hb, cbe);

  // 3b) ecoord means via CSR gather
  ecoord_gather<<<(M + 3) / 4, 256, 0, stream>>>(coord, rp_e, adj_e, ecoord, M);

  // 4) all gathers in one launch (half-wave per row)
  const int nbNode = (N + 7) / 8, nbGcnN = (N + 7) / 8, nbGcnM = (M + 7) / 8,
            nbHedge = (M + 7) / 8;
  fused_gathers<<<nbNode + nbGcnN + nbGcnM + nbHedge, 256, 0, stream>>>(
      ew, xw, coord, ecoord, rp_n, adj_n, z_conv, outc, N, nbNode, xw2, rp_gx, adj_gx,
      rs_gx, bx, outz, nbGcnN, ew2, rp_ge, adj_ge, rs_ge, beg, oute, M, nbGcnM, rp_e,
      adj_e, e_conv);

  // 5) barlow gram partials (pool buffers dead now)
  gram_partial2<<<GPN + GPM, 256, 0, stream>>>(outz, z_conv, N, gpartA, oute, e_conv,
                                               M, gpartB, st, GPN);

  // 6) gram reduce || layernorm+gelu+residual
  const int lnA = (N + 3) / 4;
  fused_reduce_ln<<<(GPN / RGRP + GPM / RGRP) * 16 + lnA + (M + 3) / 4, 256, 0,
                    stream>>>(gpartA, G1, gpartB, G2, z_conv, x, outz, N, lnA, e_conv,
                              hf, oute, M, lng, lnb);

  // 7) barlow finalize || segment pooling
  const int spA = (N + 127) / 128, spB = (M + 127) / 128;
  fused_fin_pool<<<2 + spA + spB, 256, 0, stream>>>(G1, G2, st, (float)N, (float)M,
                                                    outbt, outz, nb, N, spA, zg, oute,
                                                    hb, M, eg_p);

  graph_gemm<<<NB, 128, 0, stream>>>(zg, eg_p, cbn, cbe, Wf, bf, outg);
}

// Round 14
// 331.343 us; speedup vs baseline: 1.0256x; 1.0256x over previous
//
#include <hip/hip_runtime.h>
#include <hip/hip_bf16.h>

#define NB 32       // num_graphs
#define GPN 448     // split-K parts for gram (N side)
#define GPM 80      // split-K parts for gram (M side)
#define RGRP 16     // partials reduced per block in gram reduce

__device__ __forceinline__ float wave_sum(float v) {
#pragma unroll
  for (int off = 32; off; off >>= 1) v += __shfl_xor(v, off);
  return v;
}
__device__ __forceinline__ float half_sum(float v) {  // reduce within 32-lane group
#pragma unroll
  for (int off = 16; off; off >>= 1) v += __shfl_xor(v, off);
  return v;
}
__device__ __forceinline__ int wave_sum_i(int v) {
#pragma unroll
  for (int off = 32; off; off >>= 1) v += __shfl_xor(v, off);
  return v;
}

__device__ __forceinline__ float bf2f(unsigned short u) {
  return __uint_as_float(((unsigned int)u) << 16);
}
__device__ __forceinline__ unsigned short f2bf(float f) {  // RNE
  unsigned int v = __float_as_uint(f);
  return (unsigned short)((v + 0x7FFFu + ((v >> 16) & 1u)) >> 16);
}

// ---- count/rank pass: STANDALONE, int atomics only, 8 items/thread ----
__global__ void count_kernel(const int* __restrict__ ni, const int* __restrict__ ei,
                             int nnz, const int* __restrict__ xx, int eg,
                             const int* __restrict__ ee, int eeN, int* cnt_n,
                             int* cnt_e, int* cnt_gx, int* cnt_ge, int* rank_pn,
                             int* rank_pe, int* rank_g, int* rank_h) {
  int i = blockIdx.x * 2048 + (int)threadIdx.x;
#pragma unroll
  for (int k = 0; k < 8; k++, i += 256) {
    if (i < nnz) {
      const int n = ni[i], e = ei[i];
      rank_pn[i] = atomicAdd(&cnt_n[n], 1);
      rank_pe[i] = atomicAdd(&cnt_e[e], 1);
    } else if (i < nnz + eg) {
      const int j = i - nnz;
      rank_g[j] = atomicAdd(&cnt_gx[xx[eg + j]], 1);
    } else if (i < nnz + eg + eeN) {
      const int j = i - nnz - eg;
      rank_h[j] = atomicAdd(&cnt_ge[ee[eeN + j]], 1);
    }
  }
}

// ---- dual GEMM body: out1 = bf16(X@W1 + b1), out2 = bf16(X@W2) ----
// 64-row tile staged as bf16 in LDS (16.9KB -> ~9 blocks/CU), f32 accumulate.
__device__ __forceinline__ void gemm_body(const float* __restrict__ X,
                                          const float* __restrict__ W1,
                                          const float* __restrict__ b1,
                                          unsigned short* __restrict__ out1,
                                          const float* __restrict__ W2,
                                          unsigned short* __restrict__ out2, int rows,
                                          int blk, unsigned short (*xs)[132]) {
  const int t = threadIdx.x;
  const int c4 = t & 31;
  const int rg = t >> 5;
  const int r0 = blk * 64;
#pragma unroll
  for (int i = 0; i < 8; i++) {
    const int idx = t + i * 256;
    const int row = idx >> 5, cc = idx & 31;
    const int gr = r0 + row;
    float4 v = make_float4(0.f, 0.f, 0.f, 0.f);
    if (gr < rows) v = ((const float4*)X)[(size_t)gr * 32 + cc];
    ushort4 u;
    u.x = f2bf(v.x); u.y = f2bf(v.y); u.z = f2bf(v.z); u.w = f2bf(v.w);
    *(ushort4*)&xs[row][cc * 4] = u;
  }
  __syncthreads();
  const float4* W1v = (const float4*)W1;
  const float4* W2v = (const float4*)W2;
  const float4 b4 = ((const float4*)b1)[c4];
  float4 acc1[8], acc2[8];
#pragma unroll
  for (int i = 0; i < 8; i++) {
    acc1[i] = b4;
    acc2[i] = make_float4(0.f, 0.f, 0.f, 0.f);
  }
  const int rbase = rg * 8;
#pragma unroll 2
  for (int k = 0; k < 128; k++) {
    const float4 w1 = W1v[k * 32 + c4];
    const float4 w2 = W2v[k * 32 + c4];
#pragma unroll
    for (int i = 0; i < 8; i++) {
      const float xv = bf2f(xs[rbase + i][k]);
      acc1[i].x = fmaf(xv, w1.x, acc1[i].x);
      acc1[i].y = fmaf(xv, w1.y, acc1[i].y);
      acc1[i].z = fmaf(xv, w1.z, acc1[i].z);
      acc1[i].w = fmaf(xv, w1.w, acc1[i].w);
      acc2[i].x = fmaf(xv, w2.x, acc2[i].x);
      acc2[i].y = fmaf(xv, w2.y, acc2[i].y);
      acc2[i].z = fmaf(xv, w2.z, acc2[i].z);
      acc2[i].w = fmaf(xv, w2.w, acc2[i].w);
    }
  }
#pragma unroll
  for (int i = 0; i < 8; i++) {
    const int gr = r0 + rbase + i;
    if (gr < rows) {
      ushort4 o1, o2;
      o1.x = f2bf(acc1[i].x); o1.y = f2bf(acc1[i].y);
      o1.z = f2bf(acc1[i].z); o1.w = f2bf(acc1[i].w);
      o2.x = f2bf(acc2[i].x); o2.y = f2bf(acc2[i].y);
      o2.z = f2bf(acc2[i].z); o2.w = f2bf(acc2[i].w);
      ((ushort4*)out1)[(size_t)gr * 32 + c4] = o1;
      ((ushort4*)out2)[(size_t)gr * 32 + c4] = o2;
    }
  }
}

// ---- multi-block segmented exclusive scan over the 4 count arrays ----
__global__ __launch_bounds__(256) void scan_partial(
    const int* __restrict__ c0, int n0, const int* __restrict__ c1, int n1,
    const int* __restrict__ c2, int n2, const int* __restrict__ c3, int n3,
    int nb0, int nb1, int nb2, int nb3, int* __restrict__ bsums) {
  const int gb = blockIdx.x;
  const int* cnt;
  int lb, n;
  if (gb < nb0) { cnt = c0; lb = gb; n = n0; }
  else if (gb < nb0 + nb1) { cnt = c1; lb = gb - nb0; n = n1; }
  else if (gb < nb0 + nb1 + nb2) { cnt = c2; lb = gb - nb0 - nb1; n = n2; }
  else { cnt = c3; lb = gb - nb0 - nb1 - nb2; n = n3; }
  const int t = threadIdx.x;
  const int base = lb * 4096 + t * 16;
  int s = 0;
#pragma unroll
  for (int i = 0; i < 16; i++) {
    const int idx = base + i;
    if (idx < n) s += cnt[idx];
  }
  const int wsum = wave_sum_i(s);
  __shared__ int wsm[4];
  if ((t & 63) == 0) wsm[t >> 6] = wsum;
  __syncthreads();
  if (t == 0) bsums[gb] = wsm[0] + wsm[1] + wsm[2] + wsm[3];
}

__global__ void scan_bsums(const int* __restrict__ bsums, int nb0, int nb1, int nb2,
                           int nb3, int* __restrict__ bbase, int* __restrict__ totals) {
  if (threadIdx.x) return;
  int segs[4] = {nb0, nb1, nb2, nb3};
  int gb = 0;
  for (int a = 0; a < 4; a++) {
    int run = 0;
    for (int i = 0; i < segs[a]; i++) {
      bbase[gb] = run;
      run += bsums[gb];
      gb++;
    }
    totals[a] = run;
  }
}

// rowptr + optional rsqrt(1+deg)
__global__ __launch_bounds__(256) void scan_final(
    int* __restrict__ c0, int* rp0, float* rs0, int n0,
    int* __restrict__ c1, int* rp1, float* rs1, int n1,
    int* __restrict__ c2, int* rp2, float* rs2, int n2,
    int* __restrict__ c3, int* rp3, float* rs3, int n3,
    int nb0, int nb1, int nb2, int nb3, const int* __restrict__ bbase,
    const int* __restrict__ totals) {
  const int gb = blockIdx.x;
  int* cnt;
  int* rp;
  float* rs;
  int lb, n, a;
  if (gb < nb0) { cnt = c0; rp = rp0; rs = rs0; lb = gb; n = n0; a = 0; }
  else if (gb < nb0 + nb1) { cnt = c1; rp = rp1; rs = rs1; lb = gb - nb0; n = n1; a = 1; }
  else if (gb < nb0 + nb1 + nb2) { cnt = c2; rp = rp2; rs = rs2; lb = gb - nb0 - nb1; n = n2; a = 2; }
  else { cnt = c3; rp = rp3; rs = rs3; lb = gb - nb0 - nb1 - nb2; n = n3; a = 3; }
  const int t = threadIdx.x;
  const int base = lb * 4096 + t * 16;
  int vals[16];
  int s = 0;
#pragma unroll
  for (int i = 0; i < 16; i++) {
    const int idx = base + i;
    vals[i] = (idx < n) ? cnt[idx] : 0;
    s += vals[i];
  }
  __shared__ int tsum[256];
  tsum[t] = s;
  __syncthreads();
  for (int off = 1; off < 256; off <<= 1) {
    const int v = (t >= off) ? tsum[t - off] : 0;
    __syncthreads();
    tsum[t] += v;
    __syncthreads();
  }
  int run = bbase[gb] + (t ? tsum[t - 1] : 0);
#pragma unroll
  for (int i = 0; i < 16; i++) {
    const int idx = base + i;
    if (idx < n) {
      rp[idx] = run;
      if (rs) rs[idx] = rsqrtf(1.f + (float)vals[i]);
      run += vals[i];
    }
  }
  if (t == 0 && lb == 0) rp[n] = totals[a];
}

// ---- GEMMs || fill (atomic-free, 8 items/thread) || batch_counts ----
__global__ __launch_bounds__(256) void fused_fill_gemm(
    const float* __restrict__ x, const float* __restrict__ Wv,
    const float* __restrict__ bv, unsigned short* __restrict__ xw,
    const float* __restrict__ Wx, unsigned short* __restrict__ xw2, int N, int nbGN,
    const float* __restrict__ hf, const float* __restrict__ We,
    const float* __restrict__ be, unsigned short* __restrict__ ew,
    const float* __restrict__ Weg, unsigned short* __restrict__ ew2, int M, int nbG,
    const int* __restrict__ ni, const int* __restrict__ ei, int nnz,
    const int* __restrict__ xx, int eg, const int* __restrict__ ee, int eeN,
    const int* __restrict__ rp_n, const int* __restrict__ rp_e,
    const int* __restrict__ rp_gx, const int* __restrict__ rp_ge,
    const int* __restrict__ rank_pn, const int* __restrict__ rank_pe,
    const int* __restrict__ rank_g, const int* __restrict__ rank_h, int* adj_n,
    int* adj_e, int* adj_gx, int* adj_ge, int nbFill, const int* __restrict__ nbi,
    int* cbn, const int* __restrict__ hbi, int* cbe) {
  __shared__ unsigned short xs[64][132];
  const int b = blockIdx.x;
  const int t = threadIdx.x;
  if (b < nbG) {
    if (b < nbGN)
      gemm_body(x, Wv, bv, xw, Wx, xw2, N, b, xs);
    else
      gemm_body(hf, We, be, ew, Weg, ew2, M, b - nbGN, xs);
    return;
  }
  const int fb = b - nbG;
  if (fb < nbFill) {
    int i = fb * 2048 + t;
#pragma unroll
    for (int k = 0; k < 8; k++, i += 256) {
      if (i < nnz) {
        const int n0 = ni[i], e0 = ei[i];
        adj_n[rp_n[n0] + rank_pn[i]] = e0;
        adj_e[rp_e[e0] + rank_pe[i]] = n0;
      } else if (i < nnz + eg) {
        const int j = i - nnz;
        adj_gx[rp_gx[xx[eg + j]] + rank_g[j]] = xx[j];
      } else if (i < nnz + eg + eeN) {
        const int j = i - nnz - eg;
        adj_ge[rp_ge[ee[eeN + j]] + rank_h[j]] = ee[j];
      }
    }
    return;
  }
  const bool B = (fb - nbFill) != 0;
  const int* idx = B ? hbi : nbi;
  const int nn = B ? M : N;
  int* out = B ? cbe : cbn;
  const int g = t;
  if (g >= NB) return;
  int lo = 0, hi = nn;
  while (lo < hi) { int mid = (lo + hi) >> 1; if (idx[mid] < g) lo = mid + 1; else hi = mid; }
  const int l = lo;
  lo = 0; hi = nn;
  while (lo < hi) { int mid = (lo + hi) >> 1; if (idx[mid] < g + 1) lo = mid + 1; else hi = mid; }
  out[g] = lo - l;
}

// ---- ecoord: CSR mean of member coords ----
__global__ __launch_bounds__(256) void ecoord_gather(
    const float* __restrict__ coord, const int* __restrict__ rp_e,
    const int* __restrict__ adj_e, float* __restrict__ ecoord, int m) {
  const int e = (blockIdx.x * 256 + (int)threadIdx.x) >> 6;
  const int lane = threadIdx.x & 63;
  if (e >= m) return;
  const int lo = rp_e[e], hi = rp_e[e + 1];
  float cacc = 0.f;
  for (int base = lo; base < hi; base += 64) {
    const int mm = min(64, hi - base);
    int aj = (base + lane < hi) ? adj_e[base + lane] : 0;
    for (int j = 0; j < mm; j++) {
      const int nidx = __shfl(aj, j);
      if (lane < 3) cacc += coord[nidx * 3 + lane];
    }
  }
  if (lane < 3) ecoord[e * 3 + lane] = cacc / fmaxf((float)(hi - lo), 1.f);
}

// ---- GCN gather body: HALF-WAVE per row (32 lanes x ushort4 = 256B) ----
__device__ __forceinline__ void gcn_body(const unsigned short* __restrict__ xw,
                                         const int* __restrict__ rowptr,
                                         const int* __restrict__ adj,
                                         const float* __restrict__ rs,
                                         const float* __restrict__ bias,
                                         float* __restrict__ out, int n, int lb) {
  const int r = (lb * 256 + (int)threadIdx.x) >> 5;
  const int lane = threadIdx.x & 31;
  if (r >= n) return;
  const int lo = rowptr[r], hi = rowptr[r + 1];
  const float rd = rs[r];
  float4 acc = make_float4(0.f, 0.f, 0.f, 0.f);
  for (int base = lo; base < hi; base += 32) {
    const int mm = min(32, hi - base);
    int aj = 0;
    float rj = 0.f;
    if (base + lane < hi) {
      aj = adj[base + lane];
      rj = rs[aj];
    }
    for (int j = 0; j < mm; j++) {
      const int s = __shfl(aj, j, 32);
      const float w = __shfl(rj, j, 32);
      const ushort4 u = ((const ushort4*)xw)[(size_t)s * 32 + lane];
      acc.x = fmaf(w, bf2f(u.x), acc.x);
      acc.y = fmaf(w, bf2f(u.y), acc.y);
      acc.z = fmaf(w, bf2f(u.z), acc.z);
      acc.w = fmaf(w, bf2f(u.w), acc.w);
    }
  }
  const ushort4 su = ((const ushort4*)xw)[(size_t)r * 32 + lane];
  const float4 bb = ((const float4*)bias)[lane];
  float4 o;
  o.x = fmaf(rd, acc.x, fmaf(rd * rd, bf2f(su.x), bb.x));
  o.y = fmaf(rd, acc.y, fmaf(rd * rd, bf2f(su.y), bb.y));
  o.z = fmaf(rd, acc.z, fmaf(rd * rd, bf2f(su.z), bb.z));
  o.w = fmaf(rd, acc.w, fmaf(rd * rd, bf2f(su.w), bb.w));
  ((float4*)out)[(size_t)r * 32 + lane] = o;
}

// ---- all four gathers in one launch (half-wave per row) ----
__global__ __launch_bounds__(256) void fused_gathers(
    const unsigned short* __restrict__ ew, const unsigned short* __restrict__ xw,
    const float* __restrict__ coord, const float* __restrict__ ecoord,
    const int* __restrict__ rp_n, const int* __restrict__ adj_n,
    float* __restrict__ z_conv, float* __restrict__ outc, int N, int nbNode,
    const unsigned short* __restrict__ xw2, const int* __restrict__ rp_gx,
    const int* __restrict__ adj_gx, const float* __restrict__ rs_gx,
    const float* __restrict__ bx, float* __restrict__ outz, int nbGcnN,
    const unsigned short* __restrict__ ew2, const int* __restrict__ rp_ge,
    const int* __restrict__ adj_ge, const float* __restrict__ rs_ge,
    const float* __restrict__ beg, float* __restrict__ oute, int M, int nbGcnM,
    const int* __restrict__ rp_e, const int* __restrict__ adj_e,
    float* __restrict__ e_conv) {
  const int b = blockIdx.x;
  const int t = threadIdx.x;
  const int lane = t & 31;
  if (b < nbNode) {
    const int r = (b * 256 + t) >> 5;
    if (r >= N) return;
    const int lo = rp_n[r], hi = rp_n[r + 1];
    const ushort4 au = ((const ushort4*)xw)[(size_t)r * 32 + lane];
    const float a0 = bf2f(au.x), a1 = bf2f(au.y), a2 = bf2f(au.z), a3 = bf2f(au.w);
    const float myc = (lane < 3) ? coord[r * 3 + lane] : 0.f;
    float4 acc = make_float4(0.f, 0.f, 0.f, 0.f);
    float cacc = 0.f;
    for (int base = lo; base < hi; base += 32) {
      const int mm = min(32, hi - base);
      int aj = (base + lane < hi) ? adj_n[base + lane] : 0;
      for (int j = 0; j < mm; j++) {
        const int e = __shfl(aj, j, 32);
        const ushort4 bu = ((const ushort4*)ew)[(size_t)e * 32 + lane];
        const float b0 = bf2f(bu.x), b1 = bf2f(bu.y), b2 = bf2f(bu.z), b3 = bf2f(bu.w);
        acc.x += b0;
        acc.y += b1;
        acc.z += b2;
        acc.w += b3;
        float dot = fmaf(a0, b0, fmaf(a1, b1, fmaf(a2, b2, a3 * b3)));
        dot = half_sum(dot);
        const float ph = tanhf(dot * 0.08838834764831845f);  // 1/sqrt(128)
        if (lane < 3) cacc = fmaf(myc - ecoord[e * 3 + lane], ph, cacc);
      }
    }
    const float inv = 1.f / fmaxf((float)(hi - lo), 1.f);
    float4 o;
    o.x = acc.x * inv;
    o.y = acc.y * inv;
    o.z = acc.z * inv;
    o.w = acc.w * inv;
    ((float4*)z_conv)[(size_t)r * 32 + lane] = o;
    if (lane < 3) outc[r * 3 + lane] = myc + cacc * inv;
    return;
  }
  if (b < nbNode + nbGcnN) {
    gcn_body(xw2, rp_gx, adj_gx, rs_gx, bx, outz, N, b - nbNode);
    return;
  }
  if (b < nbNode + nbGcnN + nbGcnM) {
    gcn_body(ew2, rp_ge, adj_ge, rs_ge, beg, oute, M, b - nbNode - nbGcnN);
    return;
  }
  // hedge path
  const int lb = b - nbNode - nbGcnN - nbGcnM;
  const int e = (lb * 256 + t) >> 5;
  if (e >= M) return;
  const int lo = rp_e[e], hi = rp_e[e + 1];
  float4 acc = make_float4(0.f, 0.f, 0.f, 0.f);
  for (int base = lo; base < hi; base += 32) {
    const int mm = min(32, hi - base);
    int aj = (base + lane < hi) ? adj_e[base + lane] : 0;
    for (int j = 0; j < mm; j++) {
      const int nidx = __shfl(aj, j, 32);
      const ushort4 vu = ((const ushort4*)xw)[(size_t)nidx * 32 + lane];
      acc.x += bf2f(vu.x);
      acc.y += bf2f(vu.y);
      acc.z += bf2f(vu.z);
      acc.w += bf2f(vu.w);
    }
  }
  const float inv = 1.f / fmaxf((float)(hi - lo), 1.f);
  float4 o;
  o.x = acc.x * inv;
  o.y = acc.y * inv;
  o.z = acc.z * inv;
  o.w = acc.w * inv;
  ((float4*)e_conv)[(size_t)e * 32 + lane] = o;
}

// ---------- barlow: split-K gram + fused colstats ----------
__global__ __launch_bounds__(256) void gram_partial2(
    const float* __restrict__ Z1a, const float* __restrict__ Z2a, int na,
    float* __restrict__ parta, const float* __restrict__ Z1b,
    const float* __restrict__ Z2b, int nbm, float* __restrict__ partb,
    float* __restrict__ st, int nblkA) {
  const bool A = (int)blockIdx.x < nblkA;
  const int pid = A ? blockIdx.x : blockIdx.x - nblkA;
  const float* Z1 = A ? Z1a : Z1b;
  const float* Z2 = A ? Z2a : Z2b;
  const int n = A ? na : nbm;
  const int gparts = A ? GPN : GPM;
  float* part = (A ? parta : partb) + (size_t)pid * 16384;
  float* sum1 = st + (A ? 0 : 512);
  float* ssq1 = sum1 + 128;
  float* sum2 = sum1 + 256;
  float* ssq2 = sum1 + 384;
  __shared__ float4 s1[256], s2[256];
  const int t = threadIdx.x;
  const int ti = t >> 4, tj = t & 15;
  const int rpb = (n + gparts - 1) / gparts;
  const int lo = pid * rpb, hi = min(lo + rpb, n);
  float acc[8][8];
#pragma unroll
  for (int i = 0; i < 8; i++)
#pragma unroll
    for (int j = 0; j < 8; j++) acc[i][j] = 0.f;
  float cs = 0.f, cq = 0.f;
  const float* s1f = (const float*)s1;
  const float* s2f = (const float*)s2;
  const int c = t & 127;
  const bool low = t < 128;
  for (int rb = lo; rb < hi; rb += 8) {
    const int nr = min(8, hi - rb);
    __syncthreads();
    if (t < nr * 32) {
      const int rr = rb + (t >> 5);
      s1[t] = ((const float4*)Z1)[(size_t)rr * 32 + (t & 31)];
      s2[t] = ((const float4*)Z2)[(size_t)rr * 32 + (t & 31)];
    }
    __syncthreads();
    for (int r = 0; r < nr; r++) {
      const float4 a0 = s1[r * 32 + ti * 2], a1 = s1[r * 32 + ti * 2 + 1];
      const float4 b0 = s2[r * 32 + tj * 2], b1 = s2[r * 32 + tj * 2 + 1];
      const float av[8] = {a0.x, a0.y, a0.z, a0.w, a1.x, a1.y, a1.z, a1.w};
      const float bv[8] = {b0.x, b0.y, b0.z, b0.w, b1.x, b1.y, b1.z, b1.w};
#pragma unroll
      for (int i = 0; i < 8; i++)
#pragma unroll
        for (int j = 0; j < 8; j++) acc[i][j] = fmaf(av[i], bv[j], acc[i][j]);
      const float v = low ? s1f[r * 128 + c] : s2f[r * 128 + c];
      cs += v;
      cq = fmaf(v, v, cq);
    }
  }
  float4* P = (float4*)part;
#pragma unroll
  for (int i = 0; i < 8; i++) {
    P[(ti * 8 + i) * 32 + tj * 2] = make_float4(acc[i][0], acc[i][1], acc[i][2], acc[i][3]);
    P[(ti * 8 + i) * 32 + tj * 2 + 1] = make_float4(acc[i][4], acc[i][5], acc[i][6], acc[i][7]);
  }
  if (low) {
    atomicAdd(&sum1[c], cs);
    atomicAdd(&ssq1[c], cq);
  } else {
    atomicAdd(&sum2[c], cs);
    atomicAdd(&ssq2[c], cq);
  }
}

// ---- gram hierarchical reduce + layernorm/gelu/residual, one launch ----
__global__ __launch_bounds__(256) void fused_reduce_ln(
    const float* __restrict__ parta, float* __restrict__ G1,
    const float* __restrict__ partb, float* __restrict__ G2,
    const float* __restrict__ convA, const float* __restrict__ residA,
    float* __restrict__ outA, int nA, int lnA, const float* __restrict__ convB,
    const float* __restrict__ residB, float* __restrict__ outB, int nBm,
    const float* __restrict__ g, const float* __restrict__ bvec) {
  const int b = blockIdx.x;
  const int t = threadIdx.x;
  const int NRED = (GPN / RGRP + GPM / RGRP) * 16;  // 528
  if (b < NRED) {
    const int nga = GPN / RGRP;
    const int slice = b & 15;
    const int grp = b >> 4;
    const bool A = grp < nga;
    const float* part = A ? parta : partb;
    float* G = A ? G1 : G2;
    const int g0 = (A ? grp : grp - nga) * RGRP;
    const int e = slice * 1024 + t * 4;
    float4 s = make_float4(0.f, 0.f, 0.f, 0.f);
#pragma unroll 4
    for (int p = 0; p < RGRP; p++) {
      const float4 v = *(const float4*)&part[(size_t)(g0 + p) * 16384 + e];
      s.x += v.x;
      s.y += v.y;
      s.z += v.z;
      s.w += v.w;
    }
    atomicAdd(&G[e], s.x);
    atomicAdd(&G[e + 1], s.y);
    atomicAdd(&G[e + 2], s.z);
    atomicAdd(&G[e + 3], s.w);
    return;
  }
  const int b2 = b - NRED;
  const bool A = b2 < lnA;
  const int lb = A ? b2 : b2 - lnA;
  const float* conv = A ? convA : convB;
  const float* resid = A ? residA : residB;
  float* out = A ? outA : outB;
  const int rows = A ? nA : nBm;
  const int w = (lb * 256 + t) >> 6;
  const int lane = t & 63;
  if (w >= rows) return;
  const float2 v = ((const float2*)conv)[(size_t)w * 64 + lane];
  const float m = wave_sum(v.x + v.y) * (1.f / 128.f);
  const float q = wave_sum(fmaf(v.x, v.x, v.y * v.y)) * (1.f / 128.f);
  const float rstd = rsqrtf(q - m * m + 1e-5f);
  const float2 gg = ((const float2*)g)[lane];
  const float2 bb = ((const float2*)bvec)[lane];
  const float2 rr = ((const float2*)resid)[(size_t)w * 64 + lane];
  float y0 = fmaf(gg.x, (v.x - m) * rstd, bb.x);
  float y1 = fmaf(gg.y, (v.y - m) * rstd, bb.y);
  y0 = 0.5f * y0 * (1.f + erff(y0 * 0.7071067811865476f));
  y1 = 0.5f * y1 * (1.f + erff(y1 * 0.7071067811865476f));
  float2 o;
  o.x = y0 + rr.x;
  o.y = y1 + rr.y;
  ((float2*)out)[(size_t)w * 64 + lane] = o;
}

// ---- barlow finalize + segment pooling, one launch ----
__global__ __launch_bounds__(256) void fused_fin_pool(
    const float* __restrict__ G1, const float* __restrict__ G2,
    const float* __restrict__ st, float nA, float nB, float* outbt,
    const float* __restrict__ ZA, const int* __restrict__ bidxA, int n, int spA,
    float* poolA, const float* __restrict__ ZB, const int* __restrict__ bidxB, int m,
    float* poolB) {
  __shared__ float s1s[128], m1s[128], s2s[128], m2s[128];
  __shared__ float red[256];
  const int b = blockIdx.x;
  const int t = threadIdx.x;
  if (b < 2) {
    const bool A = b == 0;
    const float* G = A ? G1 : G2;
    const float* sum1 = st + (A ? 0 : 512);
    const float* ssq1 = sum1 + 128;
    const float* sum2 = sum1 + 256;
    const float* ssq2 = sum1 + 384;
    const float nn = A ? nA : nB;
    if (t < 128) {
      const float inv_n = 1.f / nn;
      const float bnf = (nn - 1.f) * inv_n + 1e-5f;
      float mu = sum1[t] * inv_n;
      float vu = (ssq1[t] * inv_n - mu * mu) * nn / (nn - 1.f);
      s1s[t] = rsqrtf(vu * bnf);
      m1s[t] = mu;
      mu = sum2[t] * inv_n;
      vu = (ssq2[t] * inv_n - mu * mu) * nn / (nn - 1.f);
      s2s[t] = rsqrtf(vu * bnf);
      m2s[t] = mu;
    }
    __syncthreads();
    float on = 0.f, off = 0.f;
    for (int idx = t; idx < 16384; idx += 256) {
      const int i = idx >> 7, j = idx & 127;
      const float c = s1s[i] * s2s[j] * (G[idx] - nn * m1s[i] * m2s[j]) * (1.f / 32.f);
      if (i == j) {
        const float dd = c - 1.f;
        on += dd * dd;
      } else {
        off += c * c;
      }
    }
    red[t] = on + 0.005f * off;
    __syncthreads();
    for (int s = 128; s; s >>= 1) {
      if (t < s) red[t] += red[t + s];
      __syncthreads();
    }
    if (t == 0) atomicAdd(outbt, red[0]);
    return;
  }
  const int pb = b - 2;
  const bool A = pb < spA;
  const int lb = A ? pb : pb - spA;
  const float* Z = A ? ZA : ZB;
  const int* bidx = A ? bidxA : bidxB;
  const int n2 = A ? n : m;
  float* pool = A ? poolA : poolB;
  const int c = t & 127;
  const int h = t >> 7;
  const int r0 = lb * 128 + h * 64;
  const int re = min(lb * 128 + (h + 1) * 64, n2);
  if (r0 >= n2) return;
  float acc = 0.f;
  int cur = bidx[r0];
  for (int r = r0; r < re; r++) {
    const int bb = bidx[r];
    if (bb != cur) {
      atomicAdd(&pool[cur * 128 + c], acc);
      acc = 0.f;
      cur = bb;
    }
    acc += Z[(size_t)r * 128 + c];
  }
  atomicAdd(&pool[cur * 128 + c], acc);
}

__global__ __launch_bounds__(128) void graph_gemm(
    const float* __restrict__ zg, const float* __restrict__ eg,
    const int* __restrict__ cnz, const int* __restrict__ cne,
    const float* __restrict__ Wf, const float* __restrict__ bf, float* out) {
  __shared__ float cat[256];
  const int g = blockIdx.x, t = threadIdx.x;
  cat[t] = zg[g * 128 + t] / fmaxf((float)cnz[g], 1.f);
  cat[128 + t] = eg[g * 128 + t] / fmaxf((float)cne[g], 1.f);
  __syncthreads();
  float acc = bf[t];
#pragma unroll 8
  for (int k = 0; k < 256; k++) acc = fmaf(cat[k], Wf[k * 128 + t], acc);
  out[g * 128 + t] = acc;
}

extern "C" void kernel_launch(void* const* d_in, const int* in_sizes, int n_in,
                              void* d_out, int out_size, void* d_ws, size_t ws_size,
                              hipStream_t stream) {
  const float* x = (const float*)d_in[0];
  const float* hf = (const float*)d_in[1];
  const float* coord = (const float*)d_in[2];
  const int* ni = (const int*)d_in[3];
  const int* ei = (const int*)d_in[4];
  const int* nb = (const int*)d_in[5];
  const int* hb = (const int*)d_in[6];
  const int* xx = (const int*)d_in[7];
  const int* ee = (const int*)d_in[8];
  const float* Wv = (const float*)d_in[10];
  const float* bv = (const float*)d_in[11];
  const float* We = (const float*)d_in[12];
  const float* be = (const float*)d_in[13];
  const float* Wx = (const float*)d_in[14];
  const float* bx = (const float*)d_in[15];
  const float* Weg = (const float*)d_in[16];
  const float* beg = (const float*)d_in[17];
  const float* lng = (const float*)d_in[18];
  const float* lnb = (const float*)d_in[19];
  const float* Wf = (const float*)d_in[20];
  const float* bf = (const float*)d_in[21];

  const int N = in_sizes[0] / 128;
  const int M = in_sizes[1] / 128;
  const int NNZ = in_sizes[3];
  const int EG = in_sizes[7] / 2;
  const int EE = in_sizes[8] / 2;

  float* ws = (float*)d_ws;
  size_t o = 0;
  // --- pool of buffers dead by gram time (aliased as gram partials) ---
  unsigned short* xw = (unsigned short*)(ws + o);  o += (size_t)N * 64;  // bf16 N×128
  unsigned short* ew = (unsigned short*)(ws + o);  o += (size_t)M * 64;
  unsigned short* xw2 = (unsigned short*)(ws + o); o += (size_t)N * 64;
  unsigned short* ew2 = (unsigned short*)(ws + o); o += (size_t)M * 64;
  int* rank_pn = (int*)(ws + o); o += NNZ;
  int* rank_pe = (int*)(ws + o); o += NNZ;
  int* rank_g = (int*)(ws + o);  o += EG;
  int* rank_h = (int*)(ws + o);  o += EE;
  // pool >= (GPN+GPM)*16384 floats
  // --- live buffers ---
  float* z_conv = ws + o; o += (size_t)N * 128;
  float* e_conv = ws + o; o += (size_t)M * 128;
  float* rs_gx = ws + o;  o += N;
  float* rs_ge = ws + o;  o += M;
  float* ecoord = ws + o; o += (size_t)M * 3;  // written by ecoord_gather
  const size_t fz0 = o;  // zeroed float block
  float* G1 = ws + o;     o += 16384;          // accumulated by fused_reduce_ln
  float* G2 = ws + o;     o += 16384;
  float* st = ws + o;     o += 1024;
  float* zg = ws + o;     o += NB * 128;
  float* eg_p = ws + o;   o += NB * 128;
  const size_t fz1 = o;
  int* wsi = (int*)(ws + o);
  size_t oi = 0;
  int* cnt_n = wsi + oi;  oi += N;  // zeroed: counts after count_kernel
  int* cnt_e = wsi + oi;  oi += M;
  int* cnt_gx = wsi + oi; oi += N;
  int* cnt_ge = wsi + oi; oi += M;
  const size_t iz1 = oi;
  int* rp_n = wsi + oi;   oi += N + 1;
  int* rp_e = wsi + oi;   oi += M + 1;
  int* rp_gx = wsi + oi;  oi += N + 1;
  int* rp_ge = wsi + oi;  oi += M + 1;
  int* adj_n = wsi + oi;  oi += NNZ;
  int* adj_e = wsi + oi;  oi += NNZ;
  int* adj_gx = wsi + oi; oi += EG;
  int* adj_ge = wsi + oi; oi += EE;
  int* cbn = wsi + oi;    oi += NB;
  int* cbe = wsi + oi;    oi += NB;
  int* bsums = wsi + oi;  oi += 64;
  int* bbase = wsi + oi;  oi += 64;
  int* totals = wsi + oi; oi += 4;

  float* gpartA = ws;                        // GPN*16384 floats (aliases dead pool)
  float* gpartB = ws + (size_t)GPN * 16384;  // GPM*16384 floats

  float* outz = (float*)d_out;           // temporarily z_imp
  float* oute = outz + (size_t)N * 128;  // temporarily e_imp
  float* outc = oute + (size_t)M * 128;
  float* outg = outc + (size_t)N * 3;
  float* outbt = outg + NB * 128;

  hipMemsetAsync(ws + fz0, 0, (fz1 - fz0) * 4, stream);
  hipMemsetAsync(wsi, 0, iz1 * 4, stream);
  hipMemsetAsync(outbt, 0, 4, stream);

  // 1) count/rank pass (int atomics only)
  const int tot = NNZ + EG + EE;
  const int nbCnt = (tot + 2047) >> 11;
  count_kernel<<<nbCnt, 256, 0, stream>>>(ni, ei, NNZ, xx, EG, ee, EE, cnt_n, cnt_e,
                                          cnt_gx, cnt_ge, rank_pn, rank_pe, rank_g,
                                          rank_h);

  // 2) scans
  const int nb0 = (N + 4095) >> 12, nb1 = (M + 4095) >> 12;
  const int sgrid = 2 * nb0 + 2 * nb1;
  scan_partial<<<sgrid, 256, 0, stream>>>(cnt_n, N, cnt_e, M, cnt_gx, N, cnt_ge, M,
                                          nb0, nb1, nb0, nb1, bsums);
  scan_bsums<<<1, 64, 0, stream>>>(bsums, nb0, nb1, nb0, nb1, bbase, totals);
  scan_final<<<sgrid, 256, 0, stream>>>(cnt_n, rp_n, nullptr, N, cnt_e, rp_e, nullptr,
                                        M, cnt_gx, rp_gx, rs_gx, N, cnt_ge, rp_ge,
                                        rs_ge, M, nb0, nb1, nb0, nb1, bbase, totals);

  // 3) GEMMs || fill (atomic-free) || batch counts
  const int nbGN = (N + 63) / 64, nbGM = (M + 63) / 64;
  const int nbG = nbGN + nbGM;
  const int nbFill = (tot + 2047) >> 11;
  fused_fill_gemm<<<nbG + nbFill + 2, 256, 0, stream>>>(
      x, Wv, bv, xw, Wx, xw2, N, nbGN, hf, We, be, ew, Weg, ew2, M, nbG, ni, ei, NNZ,
      xx, EG, ee, EE, rp_n, rp_e, rp_gx, rp_ge, rank_pn, rank_pe, rank_g, rank_h,
      adj_n, adj_e, adj_gx, adj_ge, nbFill, nb, cbn, hb, cbe);

  // 3b) ecoord means via CSR gather
  ecoord_gather<<<(M + 3) / 4, 256, 0, stream>>>(coord, rp_e, adj_e, ecoord, M);

  // 4) all gathers in one launch (half-wave per row)
  const int nbNode = (N + 7) / 8, nbGcnN = (N + 7) / 8, nbGcnM = (M + 7) / 8,
            nbHedge = (M + 7) / 8;
  fused_gathers<<<nbNode + nbGcnN + nbGcnM + nbHedge, 256, 0, stream>>>(
      ew, xw, coord, ecoord, rp_n, adj_n, z_conv, outc, N, nbNode, xw2, rp_gx, adj_gx,
      rs_gx, bx, outz, nbGcnN, ew2, rp_ge, adj_ge, rs_ge, beg, oute, M, nbGcnM, rp_e,
      adj_e, e_conv);

  // 5) barlow gram partials (pool buffers dead now)
  gram_partial2<<<GPN + GPM, 256, 0, stream>>>(outz, z_conv, N, gpartA, oute, e_conv,
                                               M, gpartB, st, GPN);

  // 6) gram reduce || layernorm+gelu+residual
  const int lnA = (N + 3) / 4;
  fused_reduce_ln<<<(GPN / RGRP + GPM / RGRP) * 16 + lnA + (M + 3) / 4, 256, 0,
                    stream>>>(gpartA, G1, gpartB, G2, z_conv, x, outz, N, lnA, e_conv,
                              hf, oute, M, lng, lnb);

  // 7) barlow finalize || segment pooling
  const int spA = (N + 127) / 128, spB = (M + 127) / 128;
  fused_fin_pool<<<2 + spA + spB, 256, 0, stream>>>(G1, G2, st, (float)N, (float)M,
                                                    outbt, outz, nb, N, spA, zg, oute,
                                                    hb, M, eg_p);

  graph_gemm<<<NB, 128, 0, stream>>>(zg, eg_p, cbn, cbe, Wf, bf, outg);
}

// Round 15
// 329.593 us; speedup vs baseline: 1.0311x; 1.0053x over previous
//
#include <hip/hip_runtime.h>
#include <hip/hip_bf16.h>

#define NB 32       // num_graphs
#define GPN 448     // split-K parts for gram (N side)
#define GPM 80      // split-K parts for gram (M side)
#define RGRP 16     // partials reduced per block in gram reduce

__device__ __forceinline__ float wave_sum(float v) {
#pragma unroll
  for (int off = 32; off; off >>= 1) v += __shfl_xor(v, off);
  return v;
}
__device__ __forceinline__ float half_sum(float v) {  // reduce within 32-lane group
#pragma unroll
  for (int off = 16; off; off >>= 1) v += __shfl_xor(v, off);
  return v;
}
__device__ __forceinline__ int wave_sum_i(int v) {
#pragma unroll
  for (int off = 32; off; off >>= 1) v += __shfl_xor(v, off);
  return v;
}

__device__ __forceinline__ float bf2f(unsigned short u) {
  return __uint_as_float(((unsigned int)u) << 16);
}
__device__ __forceinline__ unsigned short f2bf(float f) {  // RNE
  unsigned int v = __float_as_uint(f);
  return (unsigned short)((v + 0x7FFFu + ((v >> 16) & 1u)) >> 16);
}

// ---- count/rank pass: STANDALONE, int atomics only, 8 items/thread ----
__global__ void count_kernel(const int* __restrict__ ni, const int* __restrict__ ei,
                             int nnz, const int* __restrict__ xx, int eg,
                             const int* __restrict__ ee, int eeN, int* cnt_n,
                             int* cnt_e, int* cnt_gx, int* cnt_ge, int* rank_pn,
                             int* rank_pe, int* rank_g, int* rank_h) {
  int i = blockIdx.x * 2048 + (int)threadIdx.x;
#pragma unroll
  for (int k = 0; k < 8; k++, i += 256) {
    if (i < nnz) {
      const int n = ni[i], e = ei[i];
      rank_pn[i] = atomicAdd(&cnt_n[n], 1);
      rank_pe[i] = atomicAdd(&cnt_e[e], 1);
    } else if (i < nnz + eg) {
      const int j = i - nnz;
      rank_g[j] = atomicAdd(&cnt_gx[xx[eg + j]], 1);
    } else if (i < nnz + eg + eeN) {
      const int j = i - nnz - eg;
      rank_h[j] = atomicAdd(&cnt_ge[ee[eeN + j]], 1);
    }
  }
}

// ---- dual GEMM body: out1 = bf16(X@W1 + b1), out2 = bf16(X@W2) ----
__device__ __forceinline__ void gemm_body(const float* __restrict__ X,
                                          const float* __restrict__ W1,
                                          const float* __restrict__ b1,
                                          unsigned short* __restrict__ out1,
                                          const float* __restrict__ W2,
                                          unsigned short* __restrict__ out2, int rows,
                                          int blk, unsigned short (*xs)[132]) {
  const int t = threadIdx.x;
  const int c4 = t & 31;
  const int rg = t >> 5;
  const int r0 = blk * 64;
#pragma unroll
  for (int i = 0; i < 8; i++) {
    const int idx = t + i * 256;
    const int row = idx >> 5, cc = idx & 31;
    const int gr = r0 + row;
    float4 v = make_float4(0.f, 0.f, 0.f, 0.f);
    if (gr < rows) v = ((const float4*)X)[(size_t)gr * 32 + cc];
    ushort4 u;
    u.x = f2bf(v.x); u.y = f2bf(v.y); u.z = f2bf(v.z); u.w = f2bf(v.w);
    *(ushort4*)&xs[row][cc * 4] = u;
  }
  __syncthreads();
  const float4* W1v = (const float4*)W1;
  const float4* W2v = (const float4*)W2;
  const float4 b4 = ((const float4*)b1)[c4];
  float4 acc1[8], acc2[8];
#pragma unroll
  for (int i = 0; i < 8; i++) {
    acc1[i] = b4;
    acc2[i] = make_float4(0.f, 0.f, 0.f, 0.f);
  }
  const int rbase = rg * 8;
#pragma unroll 2
  for (int k = 0; k < 128; k++) {
    const float4 w1 = W1v[k * 32 + c4];
    const float4 w2 = W2v[k * 32 + c4];
#pragma unroll
    for (int i = 0; i < 8; i++) {
      const float xv = bf2f(xs[rbase + i][k]);
      acc1[i].x = fmaf(xv, w1.x, acc1[i].x);
      acc1[i].y = fmaf(xv, w1.y, acc1[i].y);
      acc1[i].z = fmaf(xv, w1.z, acc1[i].z);
      acc1[i].w = fmaf(xv, w1.w, acc1[i].w);
      acc2[i].x = fmaf(xv, w2.x, acc2[i].x);
      acc2[i].y = fmaf(xv, w2.y, acc2[i].y);
      acc2[i].z = fmaf(xv, w2.z, acc2[i].z);
      acc2[i].w = fmaf(xv, w2.w, acc2[i].w);
    }
  }
#pragma unroll
  for (int i = 0; i < 8; i++) {
    const int gr = r0 + rbase + i;
    if (gr < rows) {
      ushort4 o1, o2;
      o1.x = f2bf(acc1[i].x); o1.y = f2bf(acc1[i].y);
      o1.z = f2bf(acc1[i].z); o1.w = f2bf(acc1[i].w);
      o2.x = f2bf(acc2[i].x); o2.y = f2bf(acc2[i].y);
      o2.z = f2bf(acc2[i].z); o2.w = f2bf(acc2[i].w);
      ((ushort4*)out1)[(size_t)gr * 32 + c4] = o1;
      ((ushort4*)out2)[(size_t)gr * 32 + c4] = o2;
    }
  }
}

// ---- multi-block segmented exclusive scan over the 4 count arrays ----
__global__ __launch_bounds__(256) void scan_partial(
    const int* __restrict__ c0, int n0, const int* __restrict__ c1, int n1,
    const int* __restrict__ c2, int n2, const int* __restrict__ c3, int n3,
    int nb0, int nb1, int nb2, int nb3, int* __restrict__ bsums) {
  const int gb = blockIdx.x;
  const int* cnt;
  int lb, n;
  if (gb < nb0) { cnt = c0; lb = gb; n = n0; }
  else if (gb < nb0 + nb1) { cnt = c1; lb = gb - nb0; n = n1; }
  else if (gb < nb0 + nb1 + nb2) { cnt = c2; lb = gb - nb0 - nb1; n = n2; }
  else { cnt = c3; lb = gb - nb0 - nb1 - nb2; n = n3; }
  const int t = threadIdx.x;
  const int base = lb * 4096 + t * 16;
  int s = 0;
#pragma unroll
  for (int i = 0; i < 16; i++) {
    const int idx = base + i;
    if (idx < n) s += cnt[idx];
  }
  const int wsum = wave_sum_i(s);
  __shared__ int wsm[4];
  if ((t & 63) == 0) wsm[t >> 6] = wsum;
  __syncthreads();
  if (t == 0) bsums[gb] = wsm[0] + wsm[1] + wsm[2] + wsm[3];
}

__global__ void scan_bsums(const int* __restrict__ bsums, int nb0, int nb1, int nb2,
                           int nb3, int* __restrict__ bbase, int* __restrict__ totals) {
  if (threadIdx.x) return;
  int segs[4] = {nb0, nb1, nb2, nb3};
  int gb = 0;
  for (int a = 0; a < 4; a++) {
    int run = 0;
    for (int i = 0; i < segs[a]; i++) {
      bbase[gb] = run;
      run += bsums[gb];
      gb++;
    }
    totals[a] = run;
  }
}

// rowptr + optional rsqrt(1+deg)
__global__ __launch_bounds__(256) void scan_final(
    int* __restrict__ c0, int* rp0, float* rs0, int n0,
    int* __restrict__ c1, int* rp1, float* rs1, int n1,
    int* __restrict__ c2, int* rp2, float* rs2, int n2,
    int* __restrict__ c3, int* rp3, float* rs3, int n3,
    int nb0, int nb1, int nb2, int nb3, const int* __restrict__ bbase,
    const int* __restrict__ totals) {
  const int gb = blockIdx.x;
  int* cnt;
  int* rp;
  float* rs;
  int lb, n, a;
  if (gb < nb0) { cnt = c0; rp = rp0; rs = rs0; lb = gb; n = n0; a = 0; }
  else if (gb < nb0 + nb1) { cnt = c1; rp = rp1; rs = rs1; lb = gb - nb0; n = n1; a = 1; }
  else if (gb < nb0 + nb1 + nb2) { cnt = c2; rp = rp2; rs = rs2; lb = gb - nb0 - nb1; n = n2; a = 2; }
  else { cnt = c3; rp = rp3; rs = rs3; lb = gb - nb0 - nb1 - nb2; n = n3; a = 3; }
  const int t = threadIdx.x;
  const int base = lb * 4096 + t * 16;
  int vals[16];
  int s = 0;
#pragma unroll
  for (int i = 0; i < 16; i++) {
    const int idx = base + i;
    vals[i] = (idx < n) ? cnt[idx] : 0;
    s += vals[i];
  }
  __shared__ int tsum[256];
  tsum[t] = s;
  __syncthreads();
  for (int off = 1; off < 256; off <<= 1) {
    const int v = (t >= off) ? tsum[t - off] : 0;
    __syncthreads();
    tsum[t] += v;
    __syncthreads();
  }
  int run = bbase[gb] + (t ? tsum[t - 1] : 0);
#pragma unroll
  for (int i = 0; i < 16; i++) {
    const int idx = base + i;
    if (idx < n) {
      rp[idx] = run;
      if (rs) rs[idx] = rsqrtf(1.f + (float)vals[i]);
      run += vals[i];
    }
  }
  if (t == 0 && lb == 0) rp[n] = totals[a];
}

// ---- GEMMs || fill (atomic-free, 8 items/thread) || batch_counts ----
__global__ __launch_bounds__(256) void fused_fill_gemm(
    const float* __restrict__ x, const float* __restrict__ Wv,
    const float* __restrict__ bv, unsigned short* __restrict__ xw,
    const float* __restrict__ Wx, unsigned short* __restrict__ xw2, int N, int nbGN,
    const float* __restrict__ hf, const float* __restrict__ We,
    const float* __restrict__ be, unsigned short* __restrict__ ew,
    const float* __restrict__ Weg, unsigned short* __restrict__ ew2, int M, int nbG,
    const int* __restrict__ ni, const int* __restrict__ ei, int nnz,
    const int* __restrict__ xx, int eg, const int* __restrict__ ee, int eeN,
    const int* __restrict__ rp_n, const int* __restrict__ rp_e,
    const int* __restrict__ rp_gx, const int* __restrict__ rp_ge,
    const int* __restrict__ rank_pn, const int* __restrict__ rank_pe,
    const int* __restrict__ rank_g, const int* __restrict__ rank_h, int* adj_n,
    int* adj_e, int* adj_gx, int* adj_ge, int nbFill, const int* __restrict__ nbi,
    int* cbn, const int* __restrict__ hbi, int* cbe) {
  __shared__ unsigned short xs[64][132];
  const int b = blockIdx.x;
  const int t = threadIdx.x;
  if (b < nbG) {
    if (b < nbGN)
      gemm_body(x, Wv, bv, xw, Wx, xw2, N, b, xs);
    else
      gemm_body(hf, We, be, ew, Weg, ew2, M, b - nbGN, xs);
    return;
  }
  const int fb = b - nbG;
  if (fb < nbFill) {
    int i = fb * 2048 + t;
#pragma unroll
    for (int k = 0; k < 8; k++, i += 256) {
      if (i < nnz) {
        const int n0 = ni[i], e0 = ei[i];
        adj_n[rp_n[n0] + rank_pn[i]] = e0;
        adj_e[rp_e[e0] + rank_pe[i]] = n0;
      } else if (i < nnz + eg) {
        const int j = i - nnz;
        adj_gx[rp_gx[xx[eg + j]] + rank_g[j]] = xx[j];
      } else if (i < nnz + eg + eeN) {
        const int j = i - nnz - eg;
        adj_ge[rp_ge[ee[eeN + j]] + rank_h[j]] = ee[j];
      }
    }
    return;
  }
  const bool B = (fb - nbFill) != 0;
  const int* idx = B ? hbi : nbi;
  const int nn = B ? M : N;
  int* out = B ? cbe : cbn;
  const int g = t;
  if (g >= NB) return;
  int lo = 0, hi = nn;
  while (lo < hi) { int mid = (lo + hi) >> 1; if (idx[mid] < g) lo = mid + 1; else hi = mid; }
  const int l = lo;
  lo = 0; hi = nn;
  while (lo < hi) { int mid = (lo + hi) >> 1; if (idx[mid] < g + 1) lo = mid + 1; else hi = mid; }
  out[g] = lo - l;
}

// ---- ecoord: CSR mean of member coords ----
__global__ __launch_bounds__(256) void ecoord_gather(
    const float* __restrict__ coord, const int* __restrict__ rp_e,
    const int* __restrict__ adj_e, float* __restrict__ ecoord, int m) {
  const int e = (blockIdx.x * 256 + (int)threadIdx.x) >> 6;
  const int lane = threadIdx.x & 63;
  if (e >= m) return;
  const int lo = rp_e[e], hi = rp_e[e + 1];
  float cacc = 0.f;
  for (int base = lo; base < hi; base += 64) {
    const int mm = min(64, hi - base);
    int aj = (base + lane < hi) ? adj_e[base + lane] : 0;
    for (int j = 0; j < mm; j++) {
      const int nidx = __shfl(aj, j);
      if (lane < 3) cacc += coord[nidx * 3 + lane];
    }
  }
  if (lane < 3) ecoord[e * 3 + lane] = cacc / fmaxf((float)(hi - lo), 1.f);
}

// ---- GCN gather body: HALF-WAVE per row, bf16 output ----
__device__ __forceinline__ void gcn_body(const unsigned short* __restrict__ xw,
                                         const int* __restrict__ rowptr,
                                         const int* __restrict__ adj,
                                         const float* __restrict__ rs,
                                         const float* __restrict__ bias,
                                         unsigned short* __restrict__ out, int n,
                                         int lb) {
  const int r = (lb * 256 + (int)threadIdx.x) >> 5;
  const int lane = threadIdx.x & 31;
  if (r >= n) return;
  const int lo = rowptr[r], hi = rowptr[r + 1];
  const float rd = rs[r];
  float4 acc = make_float4(0.f, 0.f, 0.f, 0.f);
  for (int base = lo; base < hi; base += 32) {
    const int mm = min(32, hi - base);
    int aj = 0;
    float rj = 0.f;
    if (base + lane < hi) {
      aj = adj[base + lane];
      rj = rs[aj];
    }
    for (int j = 0; j < mm; j++) {
      const int s = __shfl(aj, j, 32);
      const float w = __shfl(rj, j, 32);
      const ushort4 u = ((const ushort4*)xw)[(size_t)s * 32 + lane];
      acc.x = fmaf(w, bf2f(u.x), acc.x);
      acc.y = fmaf(w, bf2f(u.y), acc.y);
      acc.z = fmaf(w, bf2f(u.z), acc.z);
      acc.w = fmaf(w, bf2f(u.w), acc.w);
    }
  }
  const ushort4 su = ((const ushort4*)xw)[(size_t)r * 32 + lane];
  const float4 bb = ((const float4*)bias)[lane];
  ushort4 o;
  o.x = f2bf(fmaf(rd, acc.x, fmaf(rd * rd, bf2f(su.x), bb.x)));
  o.y = f2bf(fmaf(rd, acc.y, fmaf(rd * rd, bf2f(su.y), bb.y)));
  o.z = f2bf(fmaf(rd, acc.z, fmaf(rd * rd, bf2f(su.z), bb.z)));
  o.w = f2bf(fmaf(rd, acc.w, fmaf(rd * rd, bf2f(su.w), bb.w)));
  ((ushort4*)out)[(size_t)r * 32 + lane] = o;
}

// ---- all four gathers in one launch (half-wave per row, bf16 outputs) ----
__global__ __launch_bounds__(256) void fused_gathers(
    const unsigned short* __restrict__ ew, const unsigned short* __restrict__ xw,
    const float* __restrict__ coord, const float* __restrict__ ecoord,
    const int* __restrict__ rp_n, const int* __restrict__ adj_n,
    unsigned short* __restrict__ z_conv, float* __restrict__ outc, int N, int nbNode,
    const unsigned short* __restrict__ xw2, const int* __restrict__ rp_gx,
    const int* __restrict__ adj_gx, const float* __restrict__ rs_gx,
    const float* __restrict__ bx, unsigned short* __restrict__ zi, int nbGcnN,
    const unsigned short* __restrict__ ew2, const int* __restrict__ rp_ge,
    const int* __restrict__ adj_ge, const float* __restrict__ rs_ge,
    const float* __restrict__ beg, unsigned short* __restrict__ ei_b, int M,
    int nbGcnM, const int* __restrict__ rp_e, const int* __restrict__ adj_e,
    unsigned short* __restrict__ e_conv) {
  const int b = blockIdx.x;
  const int t = threadIdx.x;
  const int lane = t & 31;
  if (b < nbNode) {
    const int r = (b * 256 + t) >> 5;
    if (r >= N) return;
    const int lo = rp_n[r], hi = rp_n[r + 1];
    const ushort4 au = ((const ushort4*)xw)[(size_t)r * 32 + lane];
    const float a0 = bf2f(au.x), a1 = bf2f(au.y), a2 = bf2f(au.z), a3 = bf2f(au.w);
    const float myc = (lane < 3) ? coord[r * 3 + lane] : 0.f;
    float4 acc = make_float4(0.f, 0.f, 0.f, 0.f);
    float cacc = 0.f;
    for (int base = lo; base < hi; base += 32) {
      const int mm = min(32, hi - base);
      int aj = (base + lane < hi) ? adj_n[base + lane] : 0;
      for (int j = 0; j < mm; j++) {
        const int e = __shfl(aj, j, 32);
        const ushort4 bu = ((const ushort4*)ew)[(size_t)e * 32 + lane];
        const float b0 = bf2f(bu.x), b1 = bf2f(bu.y), b2 = bf2f(bu.z), b3 = bf2f(bu.w);
        acc.x += b0;
        acc.y += b1;
        acc.z += b2;
        acc.w += b3;
        float dot = fmaf(a0, b0, fmaf(a1, b1, fmaf(a2, b2, a3 * b3)));
        dot = half_sum(dot);
        const float ph = tanhf(dot * 0.08838834764831845f);  // 1/sqrt(128)
        if (lane < 3) cacc = fmaf(myc - ecoord[e * 3 + lane], ph, cacc);
      }
    }
    const float inv = 1.f / fmaxf((float)(hi - lo), 1.f);
    ushort4 o;
    o.x = f2bf(acc.x * inv);
    o.y = f2bf(acc.y * inv);
    o.z = f2bf(acc.z * inv);
    o.w = f2bf(acc.w * inv);
    ((ushort4*)z_conv)[(size_t)r * 32 + lane] = o;
    if (lane < 3) outc[r * 3 + lane] = myc + cacc * inv;
    return;
  }
  if (b < nbNode + nbGcnN) {
    gcn_body(xw2, rp_gx, adj_gx, rs_gx, bx, zi, N, b - nbNode);
    return;
  }
  if (b < nbNode + nbGcnN + nbGcnM) {
    gcn_body(ew2, rp_ge, adj_ge, rs_ge, beg, ei_b, M, b - nbNode - nbGcnN);
    return;
  }
  // hedge path
  const int lb = b - nbNode - nbGcnN - nbGcnM;
  const int e = (lb * 256 + t) >> 5;
  if (e >= M) return;
  const int lo = rp_e[e], hi = rp_e[e + 1];
  float4 acc = make_float4(0.f, 0.f, 0.f, 0.f);
  for (int base = lo; base < hi; base += 32) {
    const int mm = min(32, hi - base);
    int aj = (base + lane < hi) ? adj_e[base + lane] : 0;
    for (int j = 0; j < mm; j++) {
      const int nidx = __shfl(aj, j, 32);
      const ushort4 vu = ((const ushort4*)xw)[(size_t)nidx * 32 + lane];
      acc.x += bf2f(vu.x);
      acc.y += bf2f(vu.y);
      acc.z += bf2f(vu.z);
      acc.w += bf2f(vu.w);
    }
  }
  const float inv = 1.f / fmaxf((float)(hi - lo), 1.f);
  ushort4 o;
  o.x = f2bf(acc.x * inv);
  o.y = f2bf(acc.y * inv);
  o.z = f2bf(acc.z * inv);
  o.w = f2bf(acc.w * inv);
  ((ushort4*)e_conv)[(size_t)e * 32 + lane] = o;
}

// ---------- barlow: split-K gram (bf16 inputs) + fused colstats ----------
__global__ __launch_bounds__(256) void gram_partial2(
    const unsigned short* __restrict__ Z1a, const unsigned short* __restrict__ Z2a,
    int na, float* __restrict__ parta, const unsigned short* __restrict__ Z1b,
    const unsigned short* __restrict__ Z2b, int nbm, float* __restrict__ partb,
    float* __restrict__ st, int nblkA) {
  const bool A = (int)blockIdx.x < nblkA;
  const int pid = A ? blockIdx.x : blockIdx.x - nblkA;
  const unsigned short* Z1 = A ? Z1a : Z1b;
  const unsigned short* Z2 = A ? Z2a : Z2b;
  const int n = A ? na : nbm;
  const int gparts = A ? GPN : GPM;
  float* part = (A ? parta : partb) + (size_t)pid * 16384;
  float* sum1 = st + (A ? 0 : 512);
  float* ssq1 = sum1 + 128;
  float* sum2 = sum1 + 256;
  float* ssq2 = sum1 + 384;
  __shared__ float4 s1[256], s2[256];
  const int t = threadIdx.x;
  const int ti = t >> 4, tj = t & 15;
  const int rpb = (n + gparts - 1) / gparts;
  const int lo = pid * rpb, hi = min(lo + rpb, n);
  float acc[8][8];
#pragma unroll
  for (int i = 0; i < 8; i++)
#pragma unroll
    for (int j = 0; j < 8; j++) acc[i][j] = 0.f;
  float cs = 0.f, cq = 0.f;
  const float* s1f = (const float*)s1;
  const float* s2f = (const float*)s2;
  const int c = t & 127;
  const bool low = t < 128;
  for (int rb = lo; rb < hi; rb += 8) {
    const int nr = min(8, hi - rb);
    __syncthreads();
    if (t < nr * 16) {
      const int rr = rb + (t >> 4);
      const int seg = t & 15;
      const uint4 u1 = ((const uint4*)Z1)[(size_t)rr * 16 + seg];
      const uint4 u2 = ((const uint4*)Z2)[(size_t)rr * 16 + seg];
      float4 f;
      f.x = __uint_as_float(u1.x << 16);
      f.y = __uint_as_float(u1.x & 0xffff0000u);
      f.z = __uint_as_float(u1.y << 16);
      f.w = __uint_as_float(u1.y & 0xffff0000u);
      s1[(t >> 4) * 32 + seg * 2] = f;
      f.x = __uint_as_float(u1.z << 16);
      f.y = __uint_as_float(u1.z & 0xffff0000u);
      f.z = __uint_as_float(u1.w << 16);
      f.w = __uint_as_float(u1.w & 0xffff0000u);
      s1[(t >> 4) * 32 + seg * 2 + 1] = f;
      f.x = __uint_as_float(u2.x << 16);
      f.y = __uint_as_float(u2.x & 0xffff0000u);
      f.z = __uint_as_float(u2.y << 16);
      f.w = __uint_as_float(u2.y & 0xffff0000u);
      s2[(t >> 4) * 32 + seg * 2] = f;
      f.x = __uint_as_float(u2.z << 16);
      f.y = __uint_as_float(u2.z & 0xffff0000u);
      f.z = __uint_as_float(u2.w << 16);
      f.w = __uint_as_float(u2.w & 0xffff0000u);
      s2[(t >> 4) * 32 + seg * 2 + 1] = f;
    }
    __syncthreads();
    for (int r = 0; r < nr; r++) {
      const float4 a0 = s1[r * 32 + ti * 2], a1 = s1[r * 32 + ti * 2 + 1];
      const float4 b0 = s2[r * 32 + tj * 2], b1 = s2[r * 32 + tj * 2 + 1];
      const float av[8] = {a0.x, a0.y, a0.z, a0.w, a1.x, a1.y, a1.z, a1.w};
      const float bv[8] = {b0.x, b0.y, b0.z, b0.w, b1.x, b1.y, b1.z, b1.w};
#pragma unroll
      for (int i = 0; i < 8; i++)
#pragma unroll
        for (int j = 0; j < 8; j++) acc[i][j] = fmaf(av[i], bv[j], acc[i][j]);
      const float v = low ? s1f[r * 128 + c] : s2f[r * 128 + c];
      cs += v;
      cq = fmaf(v, v, cq);
    }
  }
  float4* P = (float4*)part;
#pragma unroll
  for (int i = 0; i < 8; i++) {
    P[(ti * 8 + i) * 32 + tj * 2] = make_float4(acc[i][0], acc[i][1], acc[i][2], acc[i][3]);
    P[(ti * 8 + i) * 32 + tj * 2 + 1] = make_float4(acc[i][4], acc[i][5], acc[i][6], acc[i][7]);
  }
  if (low) {
    atomicAdd(&sum1[c], cs);
    atomicAdd(&ssq1[c], cq);
  } else {
    atomicAdd(&sum2[c], cs);
    atomicAdd(&ssq2[c], cq);
  }
}

// ---- gram hierarchical reduce + layernorm/gelu/residual, one launch ----
__global__ __launch_bounds__(256) void fused_reduce_ln(
    const float* __restrict__ parta, float* __restrict__ G1,
    const float* __restrict__ partb, float* __restrict__ G2,
    const unsigned short* __restrict__ convA, const float* __restrict__ residA,
    float* __restrict__ outA, int nA, int lnA,
    const unsigned short* __restrict__ convB, const float* __restrict__ residB,
    float* __restrict__ outB, int nBm, const float* __restrict__ g,
    const float* __restrict__ bvec) {
  const int b = blockIdx.x;
  const int t = threadIdx.x;
  const int NRED = (GPN / RGRP + GPM / RGRP) * 16;  // 528
  if (b < NRED) {
    const int nga = GPN / RGRP;
    const int slice = b & 15;
    const int grp = b >> 4;
    const bool A = grp < nga;
    const float* part = A ? parta : partb;
    float* G = A ? G1 : G2;
    const int g0 = (A ? grp : grp - nga) * RGRP;
    const int e = slice * 1024 + t * 4;
    float4 s = make_float4(0.f, 0.f, 0.f, 0.f);
#pragma unroll 4
    for (int p = 0; p < RGRP; p++) {
      const float4 v = *(const float4*)&part[(size_t)(g0 + p) * 16384 + e];
      s.x += v.x;
      s.y += v.y;
      s.z += v.z;
      s.w += v.w;
    }
    atomicAdd(&G[e], s.x);
    atomicAdd(&G[e + 1], s.y);
    atomicAdd(&G[e + 2], s.z);
    atomicAdd(&G[e + 3], s.w);
    return;
  }
  const int b2 = b - NRED;
  const bool A = b2 < lnA;
  const int lb = A ? b2 : b2 - lnA;
  const unsigned short* conv = A ? convA : convB;
  const float* resid = A ? residA : residB;
  float* out = A ? outA : outB;
  const int rows = A ? nA : nBm;
  const int w = (lb * 256 + t) >> 6;
  const int lane = t & 63;
  if (w >= rows) return;
  const ushort2 vu = ((const ushort2*)conv)[(size_t)w * 64 + lane];
  const float2 v = make_float2(bf2f(vu.x), bf2f(vu.y));
  const float m = wave_sum(v.x + v.y) * (1.f / 128.f);
  const float q = wave_sum(fmaf(v.x, v.x, v.y * v.y)) * (1.f / 128.f);
  const float rstd = rsqrtf(q - m * m + 1e-5f);
  const float2 gg = ((const float2*)g)[lane];
  const float2 bb = ((const float2*)bvec)[lane];
  const float2 rr = ((const float2*)resid)[(size_t)w * 64 + lane];
  float y0 = fmaf(gg.x, (v.x - m) * rstd, bb.x);
  float y1 = fmaf(gg.y, (v.y - m) * rstd, bb.y);
  y0 = 0.5f * y0 * (1.f + erff(y0 * 0.7071067811865476f));
  y1 = 0.5f * y1 * (1.f + erff(y1 * 0.7071067811865476f));
  float2 o;
  o.x = y0 + rr.x;
  o.y = y1 + rr.y;
  ((float2*)out)[(size_t)w * 64 + lane] = o;
}

// ---- barlow finalize + segment pooling, one launch ----
__global__ __launch_bounds__(256) void fused_fin_pool(
    const float* __restrict__ G1, const float* __restrict__ G2,
    const float* __restrict__ st, float nA, float nB, float* outbt,
    const float* __restrict__ ZA, const int* __restrict__ bidxA, int n, int spA,
    float* poolA, const float* __restrict__ ZB, const int* __restrict__ bidxB, int m,
    float* poolB) {
  __shared__ float s1s[128], m1s[128], s2s[128], m2s[128];
  __shared__ float red[256];
  const int b = blockIdx.x;
  const int t = threadIdx.x;
  if (b < 2) {
    const bool A = b == 0;
    const float* G = A ? G1 : G2;
    const float* sum1 = st + (A ? 0 : 512);
    const float* ssq1 = sum1 + 128;
    const float* sum2 = sum1 + 256;
    const float* ssq2 = sum1 + 384;
    const float nn = A ? nA : nB;
    if (t < 128) {
      const float inv_n = 1.f / nn;
      const float bnf = (nn - 1.f) * inv_n + 1e-5f;
      float mu = sum1[t] * inv_n;
      float vu = (ssq1[t] * inv_n - mu * mu) * nn / (nn - 1.f);
      s1s[t] = rsqrtf(vu * bnf);
      m1s[t] = mu;
      mu = sum2[t] * inv_n;
      vu = (ssq2[t] * inv_n - mu * mu) * nn / (nn - 1.f);
      s2s[t] = rsqrtf(vu * bnf);
      m2s[t] = mu;
    }
    __syncthreads();
    float on = 0.f, off = 0.f;
    for (int idx = t; idx < 16384; idx += 256) {
      const int i = idx >> 7, j = idx & 127;
      const float c = s1s[i] * s2s[j] * (G[idx] - nn * m1s[i] * m2s[j]) * (1.f / 32.f);
      if (i == j) {
        const float dd = c - 1.f;
        on += dd * dd;
      } else {
        off += c * c;
      }
    }
    red[t] = on + 0.005f * off;
    __syncthreads();
    for (int s = 128; s; s >>= 1) {
      if (t < s) red[t] += red[t + s];
      __syncthreads();
    }
    if (t == 0) atomicAdd(outbt, red[0]);
    return;
  }
  const int pb = b - 2;
  const bool A = pb < spA;
  const int lb = A ? pb : pb - spA;
  const float* Z = A ? ZA : ZB;
  const int* bidx = A ? bidxA : bidxB;
  const int n2 = A ? n : m;
  float* pool = A ? poolA : poolB;
  const int c = t & 127;
  const int h = t >> 7;
  const int r0 = lb * 128 + h * 64;
  const int re = min(lb * 128 + (h + 1) * 64, n2);
  if (r0 >= n2) return;
  float acc = 0.f;
  int cur = bidx[r0];
  for (int r = r0; r < re; r++) {
    const int bb = bidx[r];
    if (bb != cur) {
      atomicAdd(&pool[cur * 128 + c], acc);
      acc = 0.f;
      cur = bb;
    }
    acc += Z[(size_t)r * 128 + c];
  }
  atomicAdd(&pool[cur * 128 + c], acc);
}

__global__ __launch_bounds__(128) void graph_gemm(
    const float* __restrict__ zg, const float* __restrict__ eg,
    const int* __restrict__ cnz, const int* __restrict__ cne,
    const float* __restrict__ Wf, const float* __restrict__ bf, float* out) {
  __shared__ float cat[256];
  const int g = blockIdx.x, t = threadIdx.x;
  cat[t] = zg[g * 128 + t] / fmaxf((float)cnz[g], 1.f);
  cat[128 + t] = eg[g * 128 + t] / fmaxf((float)cne[g], 1.f);
  __syncthreads();
  float acc = bf[t];
#pragma unroll 8
  for (int k = 0; k < 256; k++) acc = fmaf(cat[k], Wf[k * 128 + t], acc);
  out[g * 128 + t] = acc;
}

extern "C" void kernel_launch(void* const* d_in, const int* in_sizes, int n_in,
                              void* d_out, int out_size, void* d_ws, size_t ws_size,
                              hipStream_t stream) {
  const float* x = (const float*)d_in[0];
  const float* hf = (const float*)d_in[1];
  const float* coord = (const float*)d_in[2];
  const int* ni = (const int*)d_in[3];
  const int* ei = (const int*)d_in[4];
  const int* nb = (const int*)d_in[5];
  const int* hb = (const int*)d_in[6];
  const int* xx = (const int*)d_in[7];
  const int* ee = (const int*)d_in[8];
  const float* Wv = (const float*)d_in[10];
  const float* bv = (const float*)d_in[11];
  const float* We = (const float*)d_in[12];
  const float* be = (const float*)d_in[13];
  const float* Wx = (const float*)d_in[14];
  const float* bx = (const float*)d_in[15];
  const float* Weg = (const float*)d_in[16];
  const float* beg = (const float*)d_in[17];
  const float* lng = (const float*)d_in[18];
  const float* lnb = (const float*)d_in[19];
  const float* Wf = (const float*)d_in[20];
  const float* bf = (const float*)d_in[21];

  const int N = in_sizes[0] / 128;
  const int M = in_sizes[1] / 128;
  const int NNZ = in_sizes[3];
  const int EG = in_sizes[7] / 2;
  const int EE = in_sizes[8] / 2;

  float* ws = (float*)d_ws;
  size_t o = 0;
  // --- pool of buffers dead by gram time (aliased as gram partials) ---
  unsigned short* xw = (unsigned short*)(ws + o);  o += (size_t)N * 64;  // bf16 N×128
  unsigned short* ew = (unsigned short*)(ws + o);  o += (size_t)M * 64;
  unsigned short* xw2 = (unsigned short*)(ws + o); o += (size_t)N * 64;
  unsigned short* ew2 = (unsigned short*)(ws + o); o += (size_t)M * 64;
  int* rank_pn = (int*)(ws + o); o += NNZ;
  int* rank_pe = (int*)(ws + o); o += NNZ;
  int* rank_g = (int*)(ws + o);  o += EG;
  int* rank_h = (int*)(ws + o);  o += EE;
  // pool >= (GPN+GPM)*16384 floats
  // --- live buffers (bf16 features) ---
  unsigned short* z_conv = (unsigned short*)(ws + o); o += (size_t)N * 64;
  unsigned short* e_conv = (unsigned short*)(ws + o); o += (size_t)M * 64;
  unsigned short* zi_b = (unsigned short*)(ws + o);   o += (size_t)N * 64;  // z_imp
  unsigned short* ei_b = (unsigned short*)(ws + o);   o += (size_t)M * 64;  // e_imp
  float* rs_gx = ws + o;  o += N;
  float* rs_ge = ws + o;  o += M;
  float* ecoord = ws + o; o += (size_t)M * 3;  // written by ecoord_gather
  const size_t fz0 = o;  // zeroed float block
  float* G1 = ws + o;     o += 16384;          // accumulated by fused_reduce_ln
  float* G2 = ws + o;     o += 16384;
  float* st = ws + o;     o += 1024;
  float* zg = ws + o;     o += NB * 128;
  float* eg_p = ws + o;   o += NB * 128;
  const size_t fz1 = o;
  int* wsi = (int*)(ws + o);
  size_t oi = 0;
  int* cnt_n = wsi + oi;  oi += N;  // zeroed: counts after count_kernel
  int* cnt_e = wsi + oi;  oi += M;
  int* cnt_gx = wsi + oi; oi += N;
  int* cnt_ge = wsi + oi; oi += M;
  const size_t iz1 = oi;
  int* rp_n = wsi + oi;   oi += N + 1;
  int* rp_e = wsi + oi;   oi += M + 1;
  int* rp_gx = wsi + oi;  oi += N + 1;
  int* rp_ge = wsi + oi;  oi += M + 1;
  int* adj_n = wsi + oi;  oi += NNZ;
  int* adj_e = wsi + oi;  oi += NNZ;
  int* adj_gx = wsi + oi; oi += EG;
  int* adj_ge = wsi + oi; oi += EE;
  int* cbn = wsi + oi;    oi += NB;
  int* cbe = wsi + oi;    oi += NB;
  int* bsums = wsi + oi;  oi += 64;
  int* bbase = wsi + oi;  oi += 64;
  int* totals = wsi + oi; oi += 4;

  float* gpartA = ws;                        // GPN*16384 floats (aliases dead pool)
  float* gpartB = ws + (size_t)GPN * 16384;  // GPM*16384 floats

  float* outz = (float*)d_out;
  float* oute = outz + (size_t)N * 128;
  float* outc = oute + (size_t)M * 128;
  float* outg = outc + (size_t)N * 3;
  float* outbt = outg + NB * 128;

  hipMemsetAsync(ws + fz0, 0, (fz1 - fz0) * 4, stream);
  hipMemsetAsync(wsi, 0, iz1 * 4, stream);
  hipMemsetAsync(outbt, 0, 4, stream);

  // 1) count/rank pass (int atomics only)
  const int tot = NNZ + EG + EE;
  const int nbCnt = (tot + 2047) >> 11;
  count_kernel<<<nbCnt, 256, 0, stream>>>(ni, ei, NNZ, xx, EG, ee, EE, cnt_n, cnt_e,
                                          cnt_gx, cnt_ge, rank_pn, rank_pe, rank_g,
                                          rank_h);

  // 2) scans
  const int nb0 = (N + 4095) >> 12, nb1 = (M + 4095) >> 12;
  const int sgrid = 2 * nb0 + 2 * nb1;
  scan_partial<<<sgrid, 256, 0, stream>>>(cnt_n, N, cnt_e, M, cnt_gx, N, cnt_ge, M,
                                          nb0, nb1, nb0, nb1, bsums);
  scan_bsums<<<1, 64, 0, stream>>>(bsums, nb0, nb1, nb0, nb1, bbase, totals);
  scan_final<<<sgrid, 256, 0, stream>>>(cnt_n, rp_n, nullptr, N, cnt_e, rp_e, nullptr,
                                        M, cnt_gx, rp_gx, rs_gx, N, cnt_ge, rp_ge,
                                        rs_ge, M, nb0, nb1, nb0, nb1, bbase, totals);

  // 3) GEMMs || fill (atomic-free) || batch counts
  const int nbGN = (N + 63) / 64, nbGM = (M + 63) / 64;
  const int nbG = nbGN + nbGM;
  const int nbFill = (tot + 2047) >> 11;
  fused_fill_gemm<<<nbG + nbFill + 2, 256, 0, stream>>>(
      x, Wv, bv, xw, Wx, xw2, N, nbGN, hf, We, be, ew, Weg, ew2, M, nbG, ni, ei, NNZ,
      xx, EG, ee, EE, rp_n, rp_e, rp_gx, rp_ge, rank_pn, rank_pe, rank_g, rank_h,
      adj_n, adj_e, adj_gx, adj_ge, nbFill, nb, cbn, hb, cbe);

  // 3b) ecoord means via CSR gather
  ecoord_gather<<<(M + 3) / 4, 256, 0, stream>>>(coord, rp_e, adj_e, ecoord, M);

  // 4) all gathers in one launch (half-wave per row, bf16 outputs)
  const int nbNode = (N + 7) / 8, nbGcnN = (N + 7) / 8, nbGcnM = (M + 7) / 8,
            nbHedge = (M + 7) / 8;
  fused_gathers<<<nbNode + nbGcnN + nbGcnM + nbHedge, 256, 0, stream>>>(
      ew, xw, coord, ecoord, rp_n, adj_n, z_conv, outc, N, nbNode, xw2, rp_gx, adj_gx,
      rs_gx, bx, zi_b, nbGcnN, ew2, rp_ge, adj_ge, rs_ge, beg, ei_b, M, nbGcnM, rp_e,
      adj_e, e_conv);

  // 5) barlow gram partials (bf16 inputs; pool buffers dead now)
  gram_partial2<<<GPN + GPM, 256, 0, stream>>>(zi_b, z_conv, N, gpartA, ei_b, e_conv,
                                               M, gpartB, st, GPN);

  // 6) gram reduce || layernorm+gelu+residual
  const int lnA = (N + 3) / 4;
  fused_reduce_ln<<<(GPN / RGRP + GPM / RGRP) * 16 + lnA + (M + 3) / 4, 256, 0,
                    stream>>>(gpartA, G1, gpartB, G2, z_conv, x, outz, N, lnA, e_conv,
                              hf, oute, M, lng, lnb);

  // 7) barlow finalize || segment pooling
  const int spA = (N + 127) / 128, spB = (M + 127) / 128;
  fused_fin_pool<<<2 + spA + spB, 256, 0, stream>>>(G1, G2, st, (float)N, (float)M,
                                                    outbt, outz, nb, N, spA, zg, oute,
                                                    hb, M, eg_p);

  graph_gemm<<<NB, 128, 0, stream>>>(zg, eg_p, cbn, cbe, Wf, bf, outg);
}